// Round 1
// baseline (2109.300 us; speedup 1.0000x reference)
//
#include <hip/hip_runtime.h>
#include <hip/hip_bf16.h>
#include <math.h>

#define NN 10000
#define NE 160000
#define HD 128
#define NL 4
#define NG 64
#define ENC_NEG_INF 0x007FFFFFu

// monotone float -> uint encoding for atomicMax on floats (handles negatives)
static __device__ __forceinline__ unsigned enc_f32(float f) {
    unsigned b = __float_as_uint(f);
    return (b & 0x80000000u) ? ~b : (b | 0x80000000u);
}
static __device__ __forceinline__ float dec_f32(unsigned u) {
    unsigned b = (u & 0x80000000u) ? (u ^ 0x80000000u) : ~u;
    return __uint_as_float(b);
}

__global__ void embed_kernel(const int* __restrict__ x, const float* __restrict__ atom_emb,
                             float* __restrict__ h, float* __restrict__ deg) {
    int idx = blockIdx.x * 256 + threadIdx.x;
    if (idx < NN) deg[idx] = 0.f;
    if (idx < NN * HD) {
        int n = idx >> 7, f = idx & 127;
        h[idx] = atom_emb[x[n] * HD + f];
    }
}

__global__ void deg_kernel(const int* __restrict__ col, float* __restrict__ deg) {
    int e = blockIdx.x * 256 + threadIdx.x;
    if (e < NE) atomicAdd(&deg[col[e]], 1.f);
}

__global__ void facs_kernel(const float* __restrict__ deg, float* __restrict__ dinv,
                            float* __restrict__ amp, float* __restrict__ att) {
    int n = blockIdx.x * 256 + threadIdx.x;
    if (n < NN) {
        float d = deg[n];
        float logD = logf(d + 1.f);
        amp[n] = logD;                       // / AVG_D_LOG (=1.0)
        att[n] = 1.f / fmaxf(logD, 1e-8f);   // AVG_D_LOG / max(logD, eps)
        dinv[n] = 1.f / fmaxf(d, 1.f);
    }
}

__global__ void clear_agg_kernel(float* __restrict__ agg_sum, unsigned* __restrict__ agg_max) {
    int idx = blockIdx.x * 256 + threadIdx.x;
    if (idx < NN * HD) { agg_sum[idx] = 0.f; agg_max[idx] = ENC_NEG_INF; }
}

// (E,384) @ (384,128): 128 edges/block, K in 32-chunks via LDS, 8x8 micro-tile.
// z2[e] = [h[row[e]], h[col[e]], bond_emb[ea[e]]]; then atomic sum/max into agg by col.
__global__ __launch_bounds__(256) void edge_msg_kernel(
    const float* __restrict__ h, const float* __restrict__ bond_emb,
    const int* __restrict__ row, const int* __restrict__ col, const int* __restrict__ ea,
    const float* __restrict__ W, const float* __restrict__ bias,
    float* __restrict__ agg_sum, unsigned* __restrict__ agg_max)
{
    __shared__ float Bs[32 * 128];
    __shared__ float As[128][36];
    __shared__ int s_row[128], s_col[128], s_ea[128];
    int t = threadIdx.x;
    int eb = blockIdx.x * 128;
    if (t < 128) {
        s_row[t] = row[eb + t];
        s_col[t] = col[eb + t];
        s_ea[t]  = ea[eb + t];
    }
    int tx = t & 15, ty = t >> 4;
    float acc[8][8];
    #pragma unroll
    for (int i = 0; i < 8; ++i)
        #pragma unroll
        for (int j = 0; j < 8; ++j) acc[i][j] = 0.f;

    for (int k0 = 0; k0 < 384; k0 += 32) {
        __syncthreads();
        // stage W chunk: 32 rows x 128 cols
        const float4* Wg = (const float4*)(W + k0 * 128);
        float4* Bs4 = (float4*)Bs;
        #pragma unroll
        for (int q = 0; q < 4; ++q) Bs4[q * 256 + t] = Wg[q * 256 + t];
        // stage z2 chunk: 128 edges x 32 floats (2 threads/edge, 16 floats each)
        {
            int em = t >> 1, half = t & 1;
            const float* src;
            if (k0 < 128)      src = h + (size_t)s_row[em] * HD + k0;
            else if (k0 < 256) src = h + (size_t)s_col[em] * HD + (k0 - 128);
            else               src = bond_emb + (size_t)s_ea[em] * HD + (k0 - 256);
            const float4* src4 = (const float4*)src;
            #pragma unroll
            for (int q = 0; q < 4; ++q) {
                float4 v = src4[half * 4 + q];
                *(float4*)&As[em][half * 16 + q * 4] = v;
            }
        }
        __syncthreads();
        #pragma unroll
        for (int kk = 0; kk < 32; ++kk) {
            float a[8], bb[8];
            #pragma unroll
            for (int i = 0; i < 8; ++i) a[i] = As[i * 16 + ty][kk];
            #pragma unroll
            for (int j = 0; j < 8; ++j) bb[j] = Bs[kk * 128 + j * 16 + tx];
            #pragma unroll
            for (int i = 0; i < 8; ++i)
                #pragma unroll
                for (int j = 0; j < 8; ++j) acc[i][j] = fmaf(a[i], bb[j], acc[i][j]);
        }
    }
    #pragma unroll
    for (int i = 0; i < 8; ++i) {
        int e = i * 16 + ty;
        int c = s_col[e];
        float* srow = agg_sum + (size_t)c * HD;
        unsigned* mrow = agg_max + (size_t)c * HD;
        #pragma unroll
        for (int j = 0; j < 8; ++j) {
            int f = j * 16 + tx;
            float v = acc[i][j] + bias[f];
            atomicAdd(srow + f, v);
            atomicMax(mrow + f, enc_f32(v));
        }
    }
}

// (N,1280) @ (1280,128): 64 nodes/block; hcat built on the fly during LDS staging.
// hcat regions (128 wide): 0 mean,1 sum,2 max,3..5 *amp,6..8 *att,9 h_in
__global__ __launch_bounds__(256) void node_update_kernel(
    float* __restrict__ h, const float* __restrict__ agg_sum, const unsigned* __restrict__ agg_max,
    const float* __restrict__ deg, const float* __restrict__ dinv,
    const float* __restrict__ amp, const float* __restrict__ att,
    const float* __restrict__ W, const float* __restrict__ bias)
{
    __shared__ float Bs[32 * 128];
    __shared__ float As[64][36];
    int t = threadIdx.x;
    int nb = blockIdx.x * 64;
    int tx = t & 15, ty = t >> 4;
    float acc[4][8];
    #pragma unroll
    for (int i = 0; i < 4; ++i)
        #pragma unroll
        for (int j = 0; j < 8; ++j) acc[i][j] = 0.f;

    for (int k0 = 0; k0 < 1280; k0 += 32) {
        __syncthreads();
        const float4* Wg = (const float4*)(W + k0 * 128);
        float4* Bs4 = (float4*)Bs;
        #pragma unroll
        for (int q = 0; q < 4; ++q) Bs4[q * 256 + t] = Wg[q * 256 + t];
        {
            int nn = t >> 2, part = t & 3;  // 4 threads/node, 8 floats each
            int n = nb + nn;
            int region = k0 >> 7;
            int kbase = k0 & 127;
            float vals[8];
            if (n < NN) {
                if (region < 9) {
                    int ag = region % 3;   // 0 mean, 1 sum, 2 max
                    int fi = region / 3;   // 0 none, 1 amp, 2 att
                    float fac = (fi == 0) ? 1.f : (fi == 1 ? amp[n] : att[n]);
                    float d = deg[n];
                    float di = dinv[n];
                    #pragma unroll
                    for (int q = 0; q < 8; ++q) {
                        int kk = kbase + part * 8 + q;
                        size_t off = (size_t)n * HD + kk;
                        float v;
                        if (ag == 0)      v = agg_sum[off] * di;
                        else if (ag == 1) v = agg_sum[off];
                        else              v = (d > 0.f) ? dec_f32(agg_max[off]) : 0.f;
                        vals[q] = v * fac;
                    }
                } else {
                    #pragma unroll
                    for (int q = 0; q < 8; ++q)
                        vals[q] = h[(size_t)n * HD + kbase + part * 8 + q];
                }
            } else {
                #pragma unroll
                for (int q = 0; q < 8; ++q) vals[q] = 0.f;
            }
            #pragma unroll
            for (int q = 0; q < 8; ++q) As[nn][part * 8 + q] = vals[q];
        }
        __syncthreads();
        #pragma unroll
        for (int kk = 0; kk < 32; ++kk) {
            float a[4], bb[8];
            #pragma unroll
            for (int i = 0; i < 4; ++i) a[i] = As[i * 16 + ty][kk];
            #pragma unroll
            for (int j = 0; j < 8; ++j) bb[j] = Bs[kk * 128 + j * 16 + tx];
            #pragma unroll
            for (int i = 0; i < 4; ++i)
                #pragma unroll
                for (int j = 0; j < 8; ++j) acc[i][j] = fmaf(a[i], bb[j], acc[i][j]);
        }
    }
    #pragma unroll
    for (int i = 0; i < 4; ++i) {
        int n = nb + i * 16 + ty;
        if (n < NN) {
            #pragma unroll
            for (int j = 0; j < 8; ++j) {
                int f = j * 16 + tx;
                size_t off = (size_t)n * HD + f;
                h[off] = acc[i][j] + bias[f] + h[off];   // + residual
            }
        }
    }
}

__global__ void graph_init_kernel(float* __restrict__ gsum, unsigned* __restrict__ gmax,
                                  float* __restrict__ gcnt) {
    int idx = blockIdx.x * 256 + threadIdx.x;
    if (idx < NG * HD) { gsum[idx] = 0.f; gmax[idx] = ENC_NEG_INF; }
    if (idx < NG) gcnt[idx] = 0.f;
}

__global__ void graph_agg_kernel(const float* __restrict__ h, const int* __restrict__ batch,
                                 float* __restrict__ gsum, unsigned* __restrict__ gmax,
                                 float* __restrict__ gcnt) {
    int idx = blockIdx.x * 256 + threadIdx.x;
    if (idx >= NN * HD) return;
    int n = idx >> 7, f = idx & 127;
    int g = batch[n];
    float v = h[idx];
    atomicAdd(&gsum[g * HD + f], v);
    atomicMax(&gmax[g * HD + f], enc_f32(v));
    if (f == 0) atomicAdd(&gcnt[g], 1.f);
}

__global__ __launch_bounds__(128) void out_kernel(
    const float* __restrict__ gsum, const unsigned* __restrict__ gmax, const float* __restrict__ gcnt,
    const float* __restrict__ W1, const float* __restrict__ b1,
    const float* __restrict__ W2, const float* __restrict__ b2,
    float* __restrict__ out)
{
    __shared__ float r[384];
    __shared__ float tred[128];
    int g = blockIdx.x, t = threadIdx.x;
    float cnt = gcnt[g];
    #pragma unroll
    for (int p = 0; p < 3; ++p) {
        float s = gsum[g * HD + t];
        float v;
        if (p == 0)      v = s / fmaxf(cnt, 1.f);
        else if (p == 1) v = s;
        else             v = (cnt > 0.f) ? dec_f32(gmax[g * HD + t]) : 0.f;
        if (isnan(v) || isinf(v)) v = 0.f;
        r[p * 128 + t] = v;
    }
    __syncthreads();
    float acc = b1[t];
    for (int k = 0; k < 384; ++k) acc = fmaf(r[k], W1[k * HD + t], acc);
    acc = fmaxf(acc, 0.f);
    tred[t] = acc * W2[t];
    __syncthreads();
    for (int s2 = 64; s2 > 0; s2 >>= 1) {
        if (t < s2) tred[t] += tred[t + s2];
        __syncthreads();
    }
    if (t == 0) {
        float o = tred[0] + b2[0];
        if (isnan(o) || isinf(o)) o = 0.f;
        out[g] = o;
    }
}

extern "C" void kernel_launch(void* const* d_in, const int* in_sizes, int n_in,
                              void* d_out, int out_size, void* d_ws, size_t ws_size,
                              hipStream_t stream)
{
    const int* x         = (const int*)d_in[0];
    const int* ei        = (const int*)d_in[1];
    const int* ea        = (const int*)d_in[2];
    const int* batch     = (const int*)d_in[3];
    const float* atom_emb = (const float*)d_in[4];
    const float* bond_emb = (const float*)d_in[5];
    const float* pre_W   = (const float*)d_in[6];
    const float* pre_b   = (const float*)d_in[7];
    const float* post_W  = (const float*)d_in[8];
    const float* post_b  = (const float*)d_in[9];
    const float* out_W1  = (const float*)d_in[10];
    const float* out_b1  = (const float*)d_in[11];
    const float* out_W2  = (const float*)d_in[12];
    const float* out_b2  = (const float*)d_in[13];
    float* out = (float*)d_out;
    const int* row = ei;
    const int* col = ei + NE;

    char* p = (char*)d_ws;
    auto alloc = [&](size_t bytes) { char* r = p; p += (bytes + 255) & ~(size_t)255; return r; };
    float*    deg     = (float*)alloc((size_t)NN * 4);
    float*    dinv    = (float*)alloc((size_t)NN * 4);
    float*    amp     = (float*)alloc((size_t)NN * 4);
    float*    att     = (float*)alloc((size_t)NN * 4);
    float*    h       = (float*)alloc((size_t)NN * HD * 4);
    float*    agg_sum = (float*)alloc((size_t)NN * HD * 4);
    unsigned* agg_max = (unsigned*)alloc((size_t)NN * HD * 4);
    float*    gsum    = (float*)alloc((size_t)NG * HD * 4);
    unsigned* gmax    = (unsigned*)alloc((size_t)NG * HD * 4);
    float*    gcnt    = (float*)alloc((size_t)NG * 4);

    embed_kernel<<<(NN * HD) / 256, 256, 0, stream>>>(x, atom_emb, h, deg);
    deg_kernel<<<(NE + 255) / 256, 256, 0, stream>>>(col, deg);
    facs_kernel<<<(NN + 255) / 256, 256, 0, stream>>>(deg, dinv, amp, att);

    for (int l = 0; l < NL; ++l) {
        clear_agg_kernel<<<(NN * HD) / 256, 256, 0, stream>>>(agg_sum, agg_max);
        edge_msg_kernel<<<NE / 128, 256, 0, stream>>>(
            h, bond_emb, row, col, ea,
            pre_W + (size_t)l * 384 * HD, pre_b + (size_t)l * HD, agg_sum, agg_max);
        node_update_kernel<<<(NN + 63) / 64, 256, 0, stream>>>(
            h, agg_sum, agg_max, deg, dinv, amp, att,
            post_W + (size_t)l * 1280 * HD, post_b + (size_t)l * HD);
    }

    graph_init_kernel<<<(NG * HD + 255) / 256, 256, 0, stream>>>(gsum, gmax, gcnt);
    graph_agg_kernel<<<(NN * HD) / 256, 256, 0, stream>>>(h, batch, gsum, gmax, gcnt);
    out_kernel<<<NG, 128, 0, stream>>>(gsum, gmax, gcnt, out_W1, out_b1, out_W2, out_b2, out);
}

// Round 2
// 958.454 us; speedup vs baseline: 2.2007x; 2.2007x over previous
//
#include <hip/hip_runtime.h>
#include <hip/hip_bf16.h>
#include <math.h>

#define NN 10000
#define NE 160000
#define HD 128
#define NL 4
#define NG 64
#define ENC_NEG_INF 0x007FFFFFu

// monotone float -> uint encoding for atomicMax on floats (handles negatives)
static __device__ __forceinline__ unsigned enc_f32(float f) {
    unsigned b = __float_as_uint(f);
    return (b & 0x80000000u) ? ~b : (b | 0x80000000u);
}
static __device__ __forceinline__ float dec_f32(unsigned u) {
    unsigned b = (u & 0x80000000u) ? (u ^ 0x80000000u) : ~u;
    return __uint_as_float(b);
}

__global__ void embed_kernel(const int* __restrict__ x, const float* __restrict__ atom_emb,
                             float* __restrict__ h, float* __restrict__ deg,
                             int* __restrict__ cursor) {
    int idx = blockIdx.x * 256 + threadIdx.x;
    if (idx < NN) { deg[idx] = 0.f; cursor[idx] = 0; }
    if (idx < NN * HD) {
        int n = idx >> 7, f = idx & 127;
        h[idx] = atom_emb[x[n] * HD + f];
    }
}

__global__ void deg_kernel(const int* __restrict__ col, float* __restrict__ deg) {
    int e = blockIdx.x * 256 + threadIdx.x;
    if (e < NE) atomicAdd(&deg[col[e]], 1.f);
}

__global__ void facs_kernel(const float* __restrict__ deg, float* __restrict__ amp,
                            float* __restrict__ att) {
    int n = blockIdx.x * 256 + threadIdx.x;
    if (n < NN) {
        float logD = logf(deg[n] + 1.f);
        amp[n] = logD;                       // / AVG_D_LOG (=1.0)
        att[n] = 1.f / fmaxf(logD, 1e-8f);   // AVG_D_LOG / max(logD, eps)
    }
}

// exclusive prefix sum of (int)deg over NN entries, offsets[NN] = total (=NE)
__global__ __launch_bounds__(1024) void scan_kernel(const float* __restrict__ deg,
                                                    int* __restrict__ offsets) {
    __shared__ int s[1024];
    __shared__ int carry_s;
    int t = threadIdx.x;
    if (t == 0) carry_s = 0;
    __syncthreads();
    for (int c = 0; c < 10; ++c) {
        int i = c * 1024 + t;
        int v = (i < NN) ? (int)deg[i] : 0;
        s[t] = v;
        __syncthreads();
        for (int off = 1; off < 1024; off <<= 1) {
            int x2 = (t >= off) ? s[t - off] : 0;
            __syncthreads();
            s[t] += x2;
            __syncthreads();
        }
        int excl = carry_s + s[t] - v;
        if (i <= NN) offsets[i] = excl;
        __syncthreads();
        if (t == 1023) carry_s += s[1023];
        __syncthreads();
    }
}

__global__ void scatter_kernel(const int* __restrict__ row, const int* __restrict__ col,
                               const int* __restrict__ ea, const int* __restrict__ offsets,
                               int* __restrict__ cursor, int* __restrict__ perm) {
    int e = blockIdx.x * 256 + threadIdx.x;
    if (e < NE) {
        int c = col[e];
        int pos = offsets[c] + atomicAdd(&cursor[c], 1);
        perm[pos] = row[e] | (ea[e] << 14);   // row < 16384, ea < 5
    }
}

// btab[l][b][f] = bond_emb[b] @ pre_W[l][256:384] + pre_b[l]   (20 blocks x 128 thr)
__global__ void bondtab_kernel(const float* __restrict__ bond_emb,
                               const float* __restrict__ pre_W, const float* __restrict__ pre_b,
                               float* __restrict__ btab) {
    int lb = blockIdx.x;
    int l = lb / 5, b = lb % 5;
    int f = threadIdx.x;
    const float* W2 = pre_W + (size_t)l * 384 * HD + 256 * HD;
    const float* eb = bond_emb + b * HD;
    float acc = pre_b[l * HD + f];
    for (int k = 0; k < HD; ++k) acc = fmaf(eb[k], W2[k * HD + f], acc);
    btab[(l * 5 + b) * HD + f] = acc;
}

// hw[n][0:128] = h[n] @ W[0:128],  hw[n][128:256] = h[n] @ W[128:256]
// 32 nodes x 256 cols per block, 256 threads, micro 2x16.
__global__ __launch_bounds__(256) void pre_gemm_kernel(const float* __restrict__ h,
                                                       const float* __restrict__ W,
                                                       float* __restrict__ hw) {
    __shared__ float Bs[32][256];
    __shared__ float As[32][36];
    int t = threadIdx.x;
    int nb = blockIdx.x * 32;
    int tx = t & 15, ty = t >> 4;
    float acc[2][16];
    #pragma unroll
    for (int i = 0; i < 2; ++i)
        #pragma unroll
        for (int j = 0; j < 16; ++j) acc[i][j] = 0.f;

    for (int k0 = 0; k0 < 128; k0 += 32) {
        __syncthreads();
        #pragma unroll
        for (int q = 0; q < 8; ++q) {
            int flat = (q * 256 + t) * 4;
            int kkr = flat >> 8, jc = flat & 255;
            const float* src = (jc < 128) ? (W + (size_t)(k0 + kkr) * HD + jc)
                                          : (W + (size_t)(128 + k0 + kkr) * HD + (jc - 128));
            *(float4*)&Bs[kkr][jc] = *(const float4*)src;
        }
        {
            int node = t >> 3, seg = t & 7;
            int n = nb + node;
            float4 v = make_float4(0.f, 0.f, 0.f, 0.f);
            if (n < NN) v = *(const float4*)(h + (size_t)n * HD + k0 + seg * 4);
            As[node][seg * 4 + 0] = v.x;
            As[node][seg * 4 + 1] = v.y;
            As[node][seg * 4 + 2] = v.z;
            As[node][seg * 4 + 3] = v.w;
        }
        __syncthreads();
        #pragma unroll
        for (int kk = 0; kk < 32; ++kk) {
            float a0 = As[ty][kk], a1 = As[16 + ty][kk];
            #pragma unroll
            for (int j = 0; j < 16; ++j) {
                float b = Bs[kk][j * 16 + tx];
                acc[0][j] = fmaf(a0, b, acc[0][j]);
                acc[1][j] = fmaf(a1, b, acc[1][j]);
            }
        }
    }
    #pragma unroll
    for (int i = 0; i < 2; ++i) {
        int n = nb + i * 16 + ty;
        if (n < NN) {
            #pragma unroll
            for (int j = 0; j < 16; ++j) hw[(size_t)n * 256 + j * 16 + tx] = acc[i][j];
        }
    }
}

// per-node CSR aggregation: exact mean/sum/max, no atomics.
// agg[n] = [mean(128) | sum(128) | max(128)]
__global__ __launch_bounds__(256) void agg_kernel(const float* __restrict__ hw,
                                                  const float* __restrict__ btab,
                                                  const int* __restrict__ offsets,
                                                  const int* __restrict__ perm,
                                                  float* __restrict__ agg) {
    int t = threadIdx.x;
    int n = blockIdx.x * 2 + (t >> 7);
    int f = t & 127;
    if (n >= NN) return;
    int s0 = offsets[n];
    int d = offsets[n + 1] - s0;
    float sum = 0.f, mx = -INFINITY;
    int p = (d > 0) ? perm[s0] : 0;
    for (int i = 0; i < d; ++i) {
        int pn = (i + 1 < d) ? perm[s0 + i + 1] : 0;
        int r = p & 16383, b = p >> 14;
        float v = hw[(size_t)r * 256 + f] + btab[b * HD + f];
        sum += v;
        mx = fmaxf(mx, v);
        p = pn;
    }
    float c = hw[(size_t)n * 256 + 128 + f];
    float mean, so, mo;
    if (d > 0) {
        so = sum + (float)d * c;
        mean = sum / (float)d + c;
        mo = mx + c;
    } else {
        so = 0.f; mean = 0.f; mo = 0.f;
    }
    agg[(size_t)n * 384 + f] = mean;
    agg[(size_t)n * 384 + 128 + f] = so;
    agg[(size_t)n * 384 + 256 + f] = mo;
}

// (N,1280)@(1280,128) with on-the-fly hcat. 32 nodes/block, K-split by 2 (grid.y).
// hcat regions (128 wide): r<9: agg[r%3] * {1,amp,att}[r/3]; r==9: h_in.
__global__ __launch_bounds__(256) void node_gemm_kernel(
    const float* __restrict__ agg, const float* __restrict__ h,
    const float* __restrict__ amp, const float* __restrict__ att,
    const float* __restrict__ W, float* __restrict__ part) {
    __shared__ float Bs[32][128];
    __shared__ float As[32][36];
    int t = threadIdx.x;
    int nb = blockIdx.x * 32;
    int kbeg = blockIdx.y * 640;
    int tx = t & 15, ty = t >> 4;
    int node = t >> 3, seg = t & 7;
    int n = nb + node;
    float f_amp = 0.f, f_att = 0.f;
    if (n < NN) { f_amp = amp[n]; f_att = att[n]; }
    float acc[2][8];
    #pragma unroll
    for (int i = 0; i < 2; ++i)
        #pragma unroll
        for (int j = 0; j < 8; ++j) acc[i][j] = 0.f;

    for (int k0 = kbeg; k0 < kbeg + 640; k0 += 32) {
        __syncthreads();
        #pragma unroll
        for (int q = 0; q < 4; ++q) {
            int flat = (q * 256 + t) * 4;
            int kkr = flat >> 7, jc = flat & 127;
            *(float4*)&Bs[kkr][jc] = *(const float4*)(W + (size_t)(k0 + kkr) * HD + jc);
        }
        {
            int r = k0 >> 7;
            int kb = (k0 & 127) + seg * 4;
            float v0 = 0.f, v1 = 0.f, v2 = 0.f, v3 = 0.f;
            if (n < NN) {
                if (r < 9) {
                    int ag = r % 3, fi = r / 3;
                    float fac = (fi == 0) ? 1.f : ((fi == 1) ? f_amp : f_att);
                    float4 v = *(const float4*)(agg + (size_t)n * 384 + ag * 128 + kb);
                    v0 = v.x * fac; v1 = v.y * fac; v2 = v.z * fac; v3 = v.w * fac;
                } else {
                    float4 v = *(const float4*)(h + (size_t)n * HD + kb);
                    v0 = v.x; v1 = v.y; v2 = v.z; v3 = v.w;
                }
            }
            As[node][seg * 4 + 0] = v0;
            As[node][seg * 4 + 1] = v1;
            As[node][seg * 4 + 2] = v2;
            As[node][seg * 4 + 3] = v3;
        }
        __syncthreads();
        #pragma unroll
        for (int kk = 0; kk < 32; ++kk) {
            float a0 = As[ty][kk], a1 = As[16 + ty][kk];
            #pragma unroll
            for (int j = 0; j < 8; ++j) {
                float b = Bs[kk][j * 16 + tx];
                acc[0][j] = fmaf(a0, b, acc[0][j]);
                acc[1][j] = fmaf(a1, b, acc[1][j]);
            }
        }
    }
    float* po = part + (size_t)blockIdx.y * NN * HD;
    #pragma unroll
    for (int i = 0; i < 2; ++i) {
        int n2 = nb + i * 16 + ty;
        if (n2 < NN) {
            #pragma unroll
            for (int j = 0; j < 8; ++j) po[(size_t)n2 * HD + j * 16 + tx] = acc[i][j];
        }
    }
}

__global__ void reduce_kernel(const float* __restrict__ part, const float* __restrict__ bias,
                              const float* __restrict__ hin, float* __restrict__ hout) {
    int idx = blockIdx.x * 256 + threadIdx.x;
    if (idx < NN * HD) {
        int f = idx & 127;
        hout[idx] = part[idx] + part[(size_t)NN * HD + idx] + bias[f] + hin[idx];
    }
}

__global__ void graph_init_kernel(float* __restrict__ gsum, unsigned* __restrict__ gmax,
                                  float* __restrict__ gcnt) {
    int idx = blockIdx.x * 256 + threadIdx.x;
    if (idx < NG * HD) { gsum[idx] = 0.f; gmax[idx] = ENC_NEG_INF; }
    if (idx < NG) gcnt[idx] = 0.f;
}

__global__ void graph_agg_kernel(const float* __restrict__ h, const int* __restrict__ batch,
                                 float* __restrict__ gsum, unsigned* __restrict__ gmax,
                                 float* __restrict__ gcnt) {
    int idx = blockIdx.x * 256 + threadIdx.x;
    if (idx >= NN * HD) return;
    int n = idx >> 7, f = idx & 127;
    int g = batch[n];
    float v = h[idx];
    atomicAdd(&gsum[g * HD + f], v);
    atomicMax(&gmax[g * HD + f], enc_f32(v));
    if (f == 0) atomicAdd(&gcnt[g], 1.f);
}

__global__ __launch_bounds__(128) void out_kernel(
    const float* __restrict__ gsum, const unsigned* __restrict__ gmax, const float* __restrict__ gcnt,
    const float* __restrict__ W1, const float* __restrict__ b1,
    const float* __restrict__ W2, const float* __restrict__ b2,
    float* __restrict__ out)
{
    __shared__ float r[384];
    __shared__ float tred[128];
    int g = blockIdx.x, t = threadIdx.x;
    float cnt = gcnt[g];
    #pragma unroll
    for (int p = 0; p < 3; ++p) {
        float s = gsum[g * HD + t];
        float v;
        if (p == 0)      v = s / fmaxf(cnt, 1.f);
        else if (p == 1) v = s;
        else             v = (cnt > 0.f) ? dec_f32(gmax[g * HD + t]) : 0.f;
        if (isnan(v) || isinf(v)) v = 0.f;
        r[p * 128 + t] = v;
    }
    __syncthreads();
    float acc = b1[t];
    for (int k = 0; k < 384; ++k) acc = fmaf(r[k], W1[k * HD + t], acc);
    acc = fmaxf(acc, 0.f);
    tred[t] = acc * W2[t];
    __syncthreads();
    for (int s2 = 64; s2 > 0; s2 >>= 1) {
        if (t < s2) tred[t] += tred[t + s2];
        __syncthreads();
    }
    if (t == 0) {
        float o = tred[0] + b2[0];
        if (isnan(o) || isinf(o)) o = 0.f;
        out[g] = o;
    }
}

extern "C" void kernel_launch(void* const* d_in, const int* in_sizes, int n_in,
                              void* d_out, int out_size, void* d_ws, size_t ws_size,
                              hipStream_t stream)
{
    const int* x          = (const int*)d_in[0];
    const int* ei         = (const int*)d_in[1];
    const int* ea         = (const int*)d_in[2];
    const int* batch      = (const int*)d_in[3];
    const float* atom_emb = (const float*)d_in[4];
    const float* bond_emb = (const float*)d_in[5];
    const float* pre_W    = (const float*)d_in[6];
    const float* pre_b    = (const float*)d_in[7];
    const float* post_W   = (const float*)d_in[8];
    const float* post_b   = (const float*)d_in[9];
    const float* out_W1   = (const float*)d_in[10];
    const float* out_b1   = (const float*)d_in[11];
    const float* out_W2   = (const float*)d_in[12];
    const float* out_b2   = (const float*)d_in[13];
    float* out = (float*)d_out;
    const int* row = ei;
    const int* col = ei + NE;

    char* p = (char*)d_ws;
    auto alloc = [&](size_t bytes) { char* r = p; p += (bytes + 255) & ~(size_t)255; return r; };
    float*    deg     = (float*)alloc((size_t)NN * 4);
    float*    amp     = (float*)alloc((size_t)NN * 4);
    float*    att     = (float*)alloc((size_t)NN * 4);
    int*      offsets = (int*)alloc((size_t)(NN + 1) * 4);
    int*      cursor  = (int*)alloc((size_t)NN * 4);
    int*      perm    = (int*)alloc((size_t)NE * 4);
    float*    hA      = (float*)alloc((size_t)NN * HD * 4);
    float*    hB      = (float*)alloc((size_t)NN * HD * 4);
    float*    hw      = (float*)alloc((size_t)NN * 256 * 4);
    float*    agg     = (float*)alloc((size_t)NN * 384 * 4);
    float*    part    = (float*)alloc((size_t)2 * NN * HD * 4);
    float*    btab    = (float*)alloc((size_t)NL * 5 * HD * 4);
    float*    gsum    = (float*)alloc((size_t)NG * HD * 4);
    unsigned* gmax    = (unsigned*)alloc((size_t)NG * HD * 4);
    float*    gcnt    = (float*)alloc((size_t)NG * 4);

    embed_kernel<<<(NN * HD) / 256, 256, 0, stream>>>(x, atom_emb, hA, deg, cursor);
    deg_kernel<<<(NE + 255) / 256, 256, 0, stream>>>(col, deg);
    facs_kernel<<<(NN + 255) / 256, 256, 0, stream>>>(deg, amp, att);
    scan_kernel<<<1, 1024, 0, stream>>>(deg, offsets);
    scatter_kernel<<<(NE + 255) / 256, 256, 0, stream>>>(row, col, ea, offsets, cursor, perm);
    bondtab_kernel<<<NL * 5, 128, 0, stream>>>(bond_emb, pre_W, pre_b, btab);

    float* curH = hA;
    float* nxtH = hB;
    for (int l = 0; l < NL; ++l) {
        pre_gemm_kernel<<<(NN + 31) / 32, 256, 0, stream>>>(
            curH, pre_W + (size_t)l * 384 * HD, hw);
        agg_kernel<<<(NN + 1) / 2, 256, 0, stream>>>(hw, btab + (size_t)l * 5 * HD,
                                                     offsets, perm, agg);
        node_gemm_kernel<<<dim3((NN + 31) / 32, 2), 256, 0, stream>>>(
            agg, curH, amp, att, post_W + (size_t)l * 1280 * HD, part);
        reduce_kernel<<<(NN * HD) / 256, 256, 0, stream>>>(
            part, post_b + (size_t)l * HD, curH, nxtH);
        float* tmp = curH; curH = nxtH; nxtH = tmp;
    }

    graph_init_kernel<<<(NG * HD + 255) / 256, 256, 0, stream>>>(gsum, gmax, gcnt);
    graph_agg_kernel<<<(NN * HD) / 256, 256, 0, stream>>>(curH, batch, gsum, gmax, gcnt);
    out_kernel<<<NG, 128, 0, stream>>>(gsum, gmax, gcnt, out_W1, out_b1, out_W2, out_b2, out);
}

// Round 3
// 493.471 us; speedup vs baseline: 4.2744x; 1.9423x over previous
//
#include <hip/hip_runtime.h>
#include <hip/hip_bf16.h>
#include <math.h>

#define NN 10000
#define NE 160000
#define HD 128
#define NL 4
#define NG 64
#define ENC_NEG_INF 0x007FFFFFu

typedef __attribute__((ext_vector_type(8))) short bf16x8;
typedef __attribute__((ext_vector_type(4))) float f32x4;

// monotone float -> uint encoding for atomicMax on floats (handles negatives)
static __device__ __forceinline__ unsigned enc_f32(float f) {
    unsigned b = __float_as_uint(f);
    return (b & 0x80000000u) ? ~b : (b | 0x80000000u);
}
static __device__ __forceinline__ float dec_f32(unsigned u) {
    unsigned b = (u & 0x80000000u) ? (u ^ 0x80000000u) : ~u;
    return __uint_as_float(b);
}
// fp32 -> bf16 (round to nearest even), finite inputs
static __device__ __forceinline__ short f2bf(float f) {
    unsigned u = __float_as_uint(f);
    unsigned r = (u + 0x7FFFu + ((u >> 16) & 1u)) >> 16;
    return (short)r;
}

__global__ void embed_kernel(const int* __restrict__ x, const float* __restrict__ atom_emb,
                             float* __restrict__ h, float* __restrict__ deg,
                             int* __restrict__ cursor) {
    int idx = blockIdx.x * 256 + threadIdx.x;
    if (idx < NN) { deg[idx] = 0.f; cursor[idx] = 0; }
    if (idx < NN * HD) {
        int n = idx >> 7, f = idx & 127;
        h[idx] = atom_emb[x[n] * HD + f];
    }
}

__global__ void deg_kernel(const int* __restrict__ col, float* __restrict__ deg) {
    int e = blockIdx.x * 256 + threadIdx.x;
    if (e < NE) atomicAdd(&deg[col[e]], 1.f);
}

__global__ void facs_kernel(const float* __restrict__ deg, float* __restrict__ amp,
                            float* __restrict__ att) {
    int n = blockIdx.x * 256 + threadIdx.x;
    if (n < NN) {
        float logD = logf(deg[n] + 1.f);
        amp[n] = logD;                       // / AVG_D_LOG (=1.0)
        att[n] = 1.f / fmaxf(logD, 1e-8f);   // AVG_D_LOG / max(logD, eps)
    }
}

// exclusive prefix sum of (int)deg over NN entries, offsets[NN] = total (=NE)
__global__ __launch_bounds__(1024) void scan_kernel(const float* __restrict__ deg,
                                                    int* __restrict__ offsets) {
    __shared__ int s[1024];
    __shared__ int carry_s;
    int t = threadIdx.x;
    if (t == 0) carry_s = 0;
    __syncthreads();
    for (int c = 0; c < 10; ++c) {
        int i = c * 1024 + t;
        int v = (i < NN) ? (int)deg[i] : 0;
        s[t] = v;
        __syncthreads();
        for (int off = 1; off < 1024; off <<= 1) {
            int x2 = (t >= off) ? s[t - off] : 0;
            __syncthreads();
            s[t] += x2;
            __syncthreads();
        }
        int excl = carry_s + s[t] - v;
        if (i <= NN) offsets[i] = excl;
        __syncthreads();
        if (t == 1023) carry_s += s[1023];
        __syncthreads();
    }
}

__global__ void scatter_kernel(const int* __restrict__ row, const int* __restrict__ col,
                               const int* __restrict__ ea, const int* __restrict__ offsets,
                               int* __restrict__ cursor, int* __restrict__ perm) {
    int e = blockIdx.x * 256 + threadIdx.x;
    if (e < NE) {
        int c = col[e];
        int pos = offsets[c] + atomicAdd(&cursor[c], 1);
        perm[pos] = row[e] | (ea[e] << 14);   // row < 16384, ea < 5
    }
}

// btab[l][b][f] = bond_emb[b] @ pre_W[l][256:384] + pre_b[l]
__global__ void bondtab_kernel(const float* __restrict__ bond_emb,
                               const float* __restrict__ pre_W, const float* __restrict__ pre_b,
                               float* __restrict__ btab) {
    int lb = blockIdx.x;
    int l = lb / 5, b = lb % 5;
    int f = threadIdx.x;
    const float* W2 = pre_W + (size_t)l * 384 * HD + 256 * HD;
    const float* eb = bond_emb + b * HD;
    float acc = pre_b[l * HD + f];
    for (int k = 0; k < HD; ++k) acc = fmaf(eb[k], W2[k * HD + f], acc);
    btab[(l * 5 + b) * HD + f] = acc;
}

// Transposed bf16 weights:
//  pre_Wt[l][j][k] (j<256,k<128): j<128 -> pre_W[l][k][j]; else pre_W[l][128+k][j-128]
//  post_Wt[l][n][k] (n<128,k<1280): post_W[l][k][n]
__global__ void convert_w_kernel(const float* __restrict__ pre_W, const float* __restrict__ post_W,
                                 short* __restrict__ pre_Wt, short* __restrict__ post_Wt) {
    int idx = blockIdx.x * 256 + threadIdx.x;
    if (idx < NL * 256 * 128) {
        int l = idx / (256 * 128), r = idx % (256 * 128);
        int j = r >> 7, k = r & 127;
        const float* Wl = pre_W + (size_t)l * 384 * HD;
        float v = (j < HD) ? Wl[k * HD + j] : Wl[(HD + k) * HD + (j - HD)];
        pre_Wt[idx] = f2bf(v);
    }
    if (idx < NL * 128 * 1280) {
        int l = idx / (128 * 1280), r = idx % (128 * 1280);
        int n = r / 1280, k = r % 1280;
        post_Wt[idx] = f2bf(post_W[(size_t)l * 1280 * HD + (size_t)k * HD + n]);
    }
}

// hw[n][0:256] = h[n] @ [W0|W1].  M_blk=32 (2 waves), grid.y = N-half.
// MFMA 16x16x32 bf16. LDS rows padded to 40 shorts (80B) -> 2-way bank aliasing (free).
__global__ __launch_bounds__(128) void pre_gemm_mfma(const float* __restrict__ h,
                                                     const short* __restrict__ Wt,  // [256][128]
                                                     float* __restrict__ hw) {
    __shared__ short As[32 * 40];
    __shared__ short Bs[128 * 40];
    int t = threadIdx.x;
    int nb = blockIdx.x * 32;
    int half = blockIdx.y;
    int wave = t >> 6, lane = t & 63;
    int arow = t >> 2, akl = (t & 3) * 8;
    int an = nb + arow;
    bool aval = an < NN;
    int lx = lane & 15, kb = lane >> 4;
    int frow = wave * 16 + lx;
    f32x4 acc[8];
    #pragma unroll
    for (int j = 0; j < 8; ++j) acc[j] = (f32x4){0.f, 0.f, 0.f, 0.f};
    const short* Wrow = Wt + (size_t)(half * 128 + t) * 128;

    for (int k0 = 0; k0 < 128; k0 += 32) {
        __syncthreads();
        {   // stage A: 32 rows x 32 k, fp32 -> bf16
            float v[8];
            if (aval) {
                const float* src = h + (size_t)an * HD + k0 + akl;
                float4 x0 = *(const float4*)src, x1 = *(const float4*)(src + 4);
                v[0]=x0.x; v[1]=x0.y; v[2]=x0.z; v[3]=x0.w;
                v[4]=x1.x; v[5]=x1.y; v[6]=x1.z; v[7]=x1.w;
            } else {
                #pragma unroll
                for (int q = 0; q < 8; ++q) v[q] = 0.f;
            }
            bf16x8 pk;
            #pragma unroll
            for (int q = 0; q < 8; ++q) pk[q] = f2bf(v[q]);
            *(bf16x8*)&As[arow * 40 + akl] = pk;
        }
        {   // stage B: 128 cols x 32 k from Wt (bf16, contiguous)
            const short* src = Wrow + k0;
            #pragma unroll
            for (int q = 0; q < 4; ++q)
                *(bf16x8*)&Bs[t * 40 + q * 8] = *(const bf16x8*)(src + q * 8);
        }
        __syncthreads();
        bf16x8 a = *(const bf16x8*)&As[frow * 40 + kb * 8];
        #pragma unroll
        for (int j = 0; j < 8; ++j) {
            bf16x8 b = *(const bf16x8*)&Bs[(j * 16 + lx) * 40 + kb * 8];
            acc[j] = __builtin_amdgcn_mfma_f32_16x16x32_bf16(a, b, acc[j], 0, 0, 0);
        }
    }
    #pragma unroll
    for (int j = 0; j < 8; ++j) {
        int c = half * 128 + j * 16 + lx;
        #pragma unroll
        for (int r_ = 0; r_ < 4; ++r_) {
            int n2 = nb + wave * 16 + kb * 4 + r_;
            if (n2 < NN) hw[(size_t)n2 * 256 + c] = acc[j][r_];
        }
    }
}

// per-node CSR aggregation: float4 lanes + 2-edge unroll; no atomics.
// agg[n] = [mean(128) | sum(128) | max(128)]
__global__ __launch_bounds__(256) void agg_kernel(const float* __restrict__ hw,
                                                  const float* __restrict__ btab,
                                                  const int* __restrict__ offsets,
                                                  const int* __restrict__ perm,
                                                  float* __restrict__ agg) {
    int t = threadIdx.x;
    int n = blockIdx.x * 8 + (t >> 5);
    int f = (t & 31) * 4;
    if (n >= NN) return;
    int s0 = offsets[n];
    int d = offsets[n + 1] - s0;
    f32x4 sum = {0.f, 0.f, 0.f, 0.f};
    f32x4 mx = {-INFINITY, -INFINITY, -INFINITY, -INFINITY};
    int i = 0;
    for (; i + 2 <= d; i += 2) {
        int p0 = perm[s0 + i], p1 = perm[s0 + i + 1];
        f32x4 a0 = *(const f32x4*)(hw + (size_t)(p0 & 16383) * 256 + f);
        f32x4 b0 = *(const f32x4*)(btab + (p0 >> 14) * HD + f);
        f32x4 a1 = *(const f32x4*)(hw + (size_t)(p1 & 16383) * 256 + f);
        f32x4 b1 = *(const f32x4*)(btab + (p1 >> 14) * HD + f);
        f32x4 v0 = a0 + b0;
        f32x4 v1 = a1 + b1;
        sum += v0 + v1;
        #pragma unroll
        for (int q = 0; q < 4; ++q) mx[q] = fmaxf(mx[q], fmaxf(v0[q], v1[q]));
    }
    if (i < d) {
        int p0 = perm[s0 + i];
        f32x4 v0 = *(const f32x4*)(hw + (size_t)(p0 & 16383) * 256 + f)
                 + *(const f32x4*)(btab + (p0 >> 14) * HD + f);
        sum += v0;
        #pragma unroll
        for (int q = 0; q < 4; ++q) mx[q] = fmaxf(mx[q], v0[q]);
    }
    f32x4 c = *(const f32x4*)(hw + (size_t)n * 256 + 128 + f);
    f32x4 mean, so, mo;
    if (d > 0) {
        float df = (float)d, di = 1.f / df;
        so = sum + df * c;
        mean = sum * di + c;
        mo = mx + c;
    } else {
        so = (f32x4){0.f,0.f,0.f,0.f}; mean = so; mo = so;
    }
    *(f32x4*)(agg + (size_t)n * 384 + f) = mean;
    *(f32x4*)(agg + (size_t)n * 384 + 128 + f) = so;
    *(f32x4*)(agg + (size_t)n * 384 + 256 + f) = mo;
}

// (N,1280)@(1280,128), hcat on the fly, bias+residual fused. M_blk=32 (2 waves).
// hcat regions (128 wide): r<9: agg[r%3] * {1,amp,att}[r/3]; r==9: h_in.
__global__ __launch_bounds__(128) void node_gemm_mfma(
    const float* __restrict__ agg, const float* __restrict__ hin,
    const float* __restrict__ amp, const float* __restrict__ att,
    const short* __restrict__ Wt /*[128][1280]*/, const float* __restrict__ bias,
    float* __restrict__ hout) {
    __shared__ short As[32 * 40];
    __shared__ short Bs[128 * 40];
    int t = threadIdx.x;
    int nb = blockIdx.x * 32;
    int wave = t >> 6, lane = t & 63;
    int arow = t >> 2, akl = (t & 3) * 8;
    int an = nb + arow;
    bool aval = an < NN;
    float f_amp = 0.f, f_att = 0.f;
    if (aval) { f_amp = amp[an]; f_att = att[an]; }
    int lx = lane & 15, kb = lane >> 4;
    int frow = wave * 16 + lx;
    f32x4 acc[8];
    #pragma unroll
    for (int j = 0; j < 8; ++j) acc[j] = (f32x4){0.f, 0.f, 0.f, 0.f};
    const short* Wrow = Wt + (size_t)t * 1280;

    for (int k0 = 0; k0 < 1280; k0 += 32) {
        __syncthreads();
        {   // stage A: 32 rows x 32 k of hcat, fp32 -> bf16
            int r = k0 >> 7;
            float v[8];
            if (aval) {
                if (r < 9) {
                    int ag = r % 3, fi = r / 3;
                    float fac = (fi == 0) ? 1.f : ((fi == 1) ? f_amp : f_att);
                    const float* src = agg + (size_t)an * 384 + ag * 128 + (k0 & 127) + akl;
                    float4 x0 = *(const float4*)src, x1 = *(const float4*)(src + 4);
                    v[0]=x0.x*fac; v[1]=x0.y*fac; v[2]=x0.z*fac; v[3]=x0.w*fac;
                    v[4]=x1.x*fac; v[5]=x1.y*fac; v[6]=x1.z*fac; v[7]=x1.w*fac;
                } else {
                    const float* src = hin + (size_t)an * HD + (k0 & 127) + akl;
                    float4 x0 = *(const float4*)src, x1 = *(const float4*)(src + 4);
                    v[0]=x0.x; v[1]=x0.y; v[2]=x0.z; v[3]=x0.w;
                    v[4]=x1.x; v[5]=x1.y; v[6]=x1.z; v[7]=x1.w;
                }
            } else {
                #pragma unroll
                for (int q = 0; q < 8; ++q) v[q] = 0.f;
            }
            bf16x8 pk;
            #pragma unroll
            for (int q = 0; q < 8; ++q) pk[q] = f2bf(v[q]);
            *(bf16x8*)&As[arow * 40 + akl] = pk;
        }
        {   // stage B
            const short* src = Wrow + k0;
            #pragma unroll
            for (int q = 0; q < 4; ++q)
                *(bf16x8*)&Bs[t * 40 + q * 8] = *(const bf16x8*)(src + q * 8);
        }
        __syncthreads();
        bf16x8 a = *(const bf16x8*)&As[frow * 40 + kb * 8];
        #pragma unroll
        for (int j = 0; j < 8; ++j) {
            bf16x8 b = *(const bf16x8*)&Bs[(j * 16 + lx) * 40 + kb * 8];
            acc[j] = __builtin_amdgcn_mfma_f32_16x16x32_bf16(a, b, acc[j], 0, 0, 0);
        }
    }
    #pragma unroll
    for (int j = 0; j < 8; ++j) {
        int c = j * 16 + lx;
        float bc = bias[c];
        #pragma unroll
        for (int r_ = 0; r_ < 4; ++r_) {
            int n2 = nb + wave * 16 + kb * 4 + r_;
            if (n2 < NN) {
                size_t off = (size_t)n2 * HD + c;
                hout[off] = acc[j][r_] + bc + hin[off];
            }
        }
    }
}

__global__ void graph_init_kernel(float* __restrict__ gsum, unsigned* __restrict__ gmax,
                                  float* __restrict__ gcnt) {
    int idx = blockIdx.x * 256 + threadIdx.x;
    if (idx < NG * HD) { gsum[idx] = 0.f; gmax[idx] = ENC_NEG_INF; }
    if (idx < NG) gcnt[idx] = 0.f;
}

__global__ void graph_agg_kernel(const float* __restrict__ h, const int* __restrict__ batch,
                                 float* __restrict__ gsum, unsigned* __restrict__ gmax,
                                 float* __restrict__ gcnt) {
    int idx = blockIdx.x * 256 + threadIdx.x;
    if (idx >= NN * HD) return;
    int n = idx >> 7, f = idx & 127;
    int g = batch[n];
    float v = h[idx];
    atomicAdd(&gsum[g * HD + f], v);
    atomicMax(&gmax[g * HD + f], enc_f32(v));
    if (f == 0) atomicAdd(&gcnt[g], 1.f);
}

__global__ __launch_bounds__(128) void out_kernel(
    const float* __restrict__ gsum, const unsigned* __restrict__ gmax, const float* __restrict__ gcnt,
    const float* __restrict__ W1, const float* __restrict__ b1,
    const float* __restrict__ W2, const float* __restrict__ b2,
    float* __restrict__ out)
{
    __shared__ float r[384];
    __shared__ float tred[128];
    int g = blockIdx.x, t = threadIdx.x;
    float cnt = gcnt[g];
    #pragma unroll
    for (int p = 0; p < 3; ++p) {
        float s = gsum[g * HD + t];
        float v;
        if (p == 0)      v = s / fmaxf(cnt, 1.f);
        else if (p == 1) v = s;
        else             v = (cnt > 0.f) ? dec_f32(gmax[g * HD + t]) : 0.f;
        if (isnan(v) || isinf(v)) v = 0.f;
        r[p * 128 + t] = v;
    }
    __syncthreads();
    float acc = b1[t];
    for (int k = 0; k < 384; ++k) acc = fmaf(r[k], W1[k * HD + t], acc);
    acc = fmaxf(acc, 0.f);
    tred[t] = acc * W2[t];
    __syncthreads();
    for (int s2 = 64; s2 > 0; s2 >>= 1) {
        if (t < s2) tred[t] += tred[t + s2];
        __syncthreads();
    }
    if (t == 0) {
        float o = tred[0] + b2[0];
        if (isnan(o) || isinf(o)) o = 0.f;
        out[g] = o;
    }
}

extern "C" void kernel_launch(void* const* d_in, const int* in_sizes, int n_in,
                              void* d_out, int out_size, void* d_ws, size_t ws_size,
                              hipStream_t stream)
{
    const int* x          = (const int*)d_in[0];
    const int* ei         = (const int*)d_in[1];
    const int* ea         = (const int*)d_in[2];
    const int* batch      = (const int*)d_in[3];
    const float* atom_emb = (const float*)d_in[4];
    const float* bond_emb = (const float*)d_in[5];
    const float* pre_W    = (const float*)d_in[6];
    const float* pre_b    = (const float*)d_in[7];
    const float* post_W   = (const float*)d_in[8];
    const float* post_b   = (const float*)d_in[9];
    const float* out_W1   = (const float*)d_in[10];
    const float* out_b1   = (const float*)d_in[11];
    const float* out_W2   = (const float*)d_in[12];
    const float* out_b2   = (const float*)d_in[13];
    float* out = (float*)d_out;
    const int* row = ei;
    const int* col = ei + NE;

    char* p = (char*)d_ws;
    auto alloc = [&](size_t bytes) { char* r = p; p += (bytes + 255) & ~(size_t)255; return r; };
    float*    deg     = (float*)alloc((size_t)NN * 4);
    float*    amp     = (float*)alloc((size_t)NN * 4);
    float*    att     = (float*)alloc((size_t)NN * 4);
    int*      offsets = (int*)alloc((size_t)(NN + 1) * 4);
    int*      cursor  = (int*)alloc((size_t)NN * 4);
    int*      perm    = (int*)alloc((size_t)NE * 4);
    float*    hA      = (float*)alloc((size_t)NN * HD * 4);
    float*    hB      = (float*)alloc((size_t)NN * HD * 4);
    float*    hw      = (float*)alloc((size_t)NN * 256 * 4);
    float*    agg     = (float*)alloc((size_t)NN * 384 * 4);
    float*    btab    = (float*)alloc((size_t)NL * 5 * HD * 4);
    short*    pre_Wt  = (short*)alloc((size_t)NL * 256 * 128 * 2);
    short*    post_Wt = (short*)alloc((size_t)NL * 128 * 1280 * 2);
    float*    gsum    = (float*)alloc((size_t)NG * HD * 4);
    unsigned* gmax    = (unsigned*)alloc((size_t)NG * HD * 4);
    float*    gcnt    = (float*)alloc((size_t)NG * 4);

    embed_kernel<<<(NN * HD) / 256, 256, 0, stream>>>(x, atom_emb, hA, deg, cursor);
    deg_kernel<<<(NE + 255) / 256, 256, 0, stream>>>(col, deg);
    facs_kernel<<<(NN + 255) / 256, 256, 0, stream>>>(deg, amp, att);
    scan_kernel<<<1, 1024, 0, stream>>>(deg, offsets);
    scatter_kernel<<<(NE + 255) / 256, 256, 0, stream>>>(row, col, ea, offsets, cursor, perm);
    bondtab_kernel<<<NL * 5, 128, 0, stream>>>(bond_emb, pre_W, pre_b, btab);
    convert_w_kernel<<<(NL * 128 * 1280 + 255) / 256, 256, 0, stream>>>(pre_W, post_W,
                                                                        pre_Wt, post_Wt);

    float* curH = hA;
    float* nxtH = hB;
    for (int l = 0; l < NL; ++l) {
        pre_gemm_mfma<<<dim3((NN + 31) / 32, 2), 128, 0, stream>>>(
            curH, pre_Wt + (size_t)l * 256 * 128, hw);
        agg_kernel<<<(NN + 7) / 8, 256, 0, stream>>>(hw, btab + (size_t)l * 5 * HD,
                                                     offsets, perm, agg);
        node_gemm_mfma<<<(NN + 31) / 32, 128, 0, stream>>>(
            agg, curH, amp, att, post_Wt + (size_t)l * 128 * 1280,
            post_b + (size_t)l * HD, nxtH);
        float* tmp = curH; curH = nxtH; nxtH = tmp;
    }

    graph_init_kernel<<<(NG * HD + 255) / 256, 256, 0, stream>>>(gsum, gmax, gcnt);
    graph_agg_kernel<<<(NN * HD) / 256, 256, 0, stream>>>(curH, batch, gsum, gmax, gcnt);
    out_kernel<<<NG, 128, 0, stream>>>(gsum, gmax, gcnt, out_W1, out_b1, out_W2, out_b2, out);
}

// Round 4
// 398.676 us; speedup vs baseline: 5.2908x; 1.2378x over previous
//
#include <hip/hip_runtime.h>
#include <hip/hip_bf16.h>
#include <math.h>

#define NN 10000
#define NE 160000
#define HD 128
#define NL 4
#define NG 64

typedef __attribute__((ext_vector_type(8))) short bf16x8;
typedef __attribute__((ext_vector_type(4))) float f32x4;

// fp32 -> bf16 (round to nearest even), finite inputs
static __device__ __forceinline__ short f2bf(float f) {
    unsigned u = __float_as_uint(f);
    unsigned r = (u + 0x7FFFu + ((u >> 16) & 1u)) >> 16;
    return (short)r;
}

__global__ void embed_kernel(const int* __restrict__ x, const float* __restrict__ atom_emb,
                             float* __restrict__ h, float* __restrict__ deg,
                             int* __restrict__ cursor) {
    int idx = blockIdx.x * 256 + threadIdx.x;
    if (idx < NN) { deg[idx] = 0.f; cursor[idx] = 0; }
    if (idx < NN * HD) {
        int n = idx >> 7, f = idx & 127;
        h[idx] = atom_emb[x[n] * HD + f];
    }
}

__global__ void deg_kernel(const int* __restrict__ col, float* __restrict__ deg) {
    int e = blockIdx.x * 256 + threadIdx.x;
    if (e < NE) atomicAdd(&deg[col[e]], 1.f);
}

__global__ void facs_kernel(const float* __restrict__ deg, float* __restrict__ amp,
                            float* __restrict__ att) {
    int n = blockIdx.x * 256 + threadIdx.x;
    if (n < NN) {
        float logD = logf(deg[n] + 1.f);
        amp[n] = logD;                       // / AVG_D_LOG (=1.0)
        att[n] = 1.f / fmaxf(logD, 1e-8f);   // AVG_D_LOG / max(logD, eps)
    }
}

// exclusive prefix sum of (int)deg over NN entries, offsets[NN] = total (=NE)
__global__ __launch_bounds__(1024) void scan_kernel(const float* __restrict__ deg,
                                                    int* __restrict__ offsets) {
    __shared__ int s[1024];
    __shared__ int carry_s;
    int t = threadIdx.x;
    if (t == 0) carry_s = 0;
    __syncthreads();
    for (int c = 0; c < 10; ++c) {
        int i = c * 1024 + t;
        int v = (i < NN) ? (int)deg[i] : 0;
        s[t] = v;
        __syncthreads();
        for (int off = 1; off < 1024; off <<= 1) {
            int x2 = (t >= off) ? s[t - off] : 0;
            __syncthreads();
            s[t] += x2;
            __syncthreads();
        }
        int excl = carry_s + s[t] - v;
        if (i <= NN) offsets[i] = excl;
        __syncthreads();
        if (t == 1023) carry_s += s[1023];
        __syncthreads();
    }
}

__global__ void scatter_kernel(const int* __restrict__ row, const int* __restrict__ col,
                               const int* __restrict__ ea, const int* __restrict__ offsets,
                               int* __restrict__ cursor, int* __restrict__ perm) {
    int e = blockIdx.x * 256 + threadIdx.x;
    if (e < NE) {
        int c = col[e];
        int pos = offsets[c] + atomicAdd(&cursor[c], 1);
        perm[pos] = row[e] | (ea[e] << 14);   // row < 16384, ea < 5
    }
}

// btab[l][b][f] = bond_emb[b] @ pre_W[l][256:384] + pre_b[l]
__global__ void bondtab_kernel(const float* __restrict__ bond_emb,
                               const float* __restrict__ pre_W, const float* __restrict__ pre_b,
                               float* __restrict__ btab) {
    int lb = blockIdx.x;
    int l = lb / 5, b = lb % 5;
    int f = threadIdx.x;
    const float* W2 = pre_W + (size_t)l * 384 * HD + 256 * HD;
    const float* eb = bond_emb + b * HD;
    float acc = pre_b[l * HD + f];
    for (int k = 0; k < HD; ++k) acc = fmaf(eb[k], W2[k * HD + f], acc);
    btab[(l * 5 + b) * HD + f] = acc;
}

// Transposed bf16 weights:
//  pre_Wt[l][j][k] (j<256,k<128): j<128 -> pre_W[l][k][j]; else pre_W[l][128+k][j-128]
//  post_Wt[l][n][k] (n<128,k<1280): post_W[l][k][n]
__global__ void convert_w_kernel(const float* __restrict__ pre_W, const float* __restrict__ post_W,
                                 short* __restrict__ pre_Wt, short* __restrict__ post_Wt) {
    int idx = blockIdx.x * 256 + threadIdx.x;
    if (idx < NL * 256 * 128) {
        int l = idx / (256 * 128), r = idx % (256 * 128);
        int j = r >> 7, k = r & 127;
        const float* Wl = pre_W + (size_t)l * 384 * HD;
        float v = (j < HD) ? Wl[k * HD + j] : Wl[(HD + k) * HD + (j - HD)];
        pre_Wt[idx] = f2bf(v);
    }
    if (idx < NL * 128 * 1280) {
        int l = idx / (128 * 1280), r = idx % (128 * 1280);
        int n = r / 1280, k = r % 1280;
        post_Wt[idx] = f2bf(post_W[(size_t)l * 1280 * HD + (size_t)k * HD + n]);
    }
}

// hw[n][0:256] = h[n] @ [W0|W1].  M_blk=32 (2 waves), grid.y = N-half.
// MFMA 16x16x32 bf16. LDS rows padded to 40 shorts (80B) -> 2-way bank aliasing (free).
__global__ __launch_bounds__(128) void pre_gemm_mfma(const float* __restrict__ h,
                                                     const short* __restrict__ Wt,  // [256][128]
                                                     float* __restrict__ hw) {
    __shared__ short As[32 * 40];
    __shared__ short Bs[128 * 40];
    int t = threadIdx.x;
    int nb = blockIdx.x * 32;
    int half = blockIdx.y;
    int wave = t >> 6, lane = t & 63;
    int arow = t >> 2, akl = (t & 3) * 8;
    int an = nb + arow;
    bool aval = an < NN;
    int lx = lane & 15, kb = lane >> 4;
    int frow = wave * 16 + lx;
    f32x4 acc[8];
    #pragma unroll
    for (int j = 0; j < 8; ++j) acc[j] = (f32x4){0.f, 0.f, 0.f, 0.f};
    const short* Wrow = Wt + (size_t)(half * 128 + t) * 128;

    for (int k0 = 0; k0 < 128; k0 += 32) {
        __syncthreads();
        {   // stage A: 32 rows x 32 k, fp32 -> bf16
            float v[8];
            if (aval) {
                const float* src = h + (size_t)an * HD + k0 + akl;
                float4 x0 = *(const float4*)src, x1 = *(const float4*)(src + 4);
                v[0]=x0.x; v[1]=x0.y; v[2]=x0.z; v[3]=x0.w;
                v[4]=x1.x; v[5]=x1.y; v[6]=x1.z; v[7]=x1.w;
            } else {
                #pragma unroll
                for (int q = 0; q < 8; ++q) v[q] = 0.f;
            }
            bf16x8 pk;
            #pragma unroll
            for (int q = 0; q < 8; ++q) pk[q] = f2bf(v[q]);
            *(bf16x8*)&As[arow * 40 + akl] = pk;
        }
        {   // stage B: 128 cols x 32 k from Wt (bf16, contiguous)
            const short* src = Wrow + k0;
            #pragma unroll
            for (int q = 0; q < 4; ++q)
                *(bf16x8*)&Bs[t * 40 + q * 8] = *(const bf16x8*)(src + q * 8);
        }
        __syncthreads();
        bf16x8 a = *(const bf16x8*)&As[frow * 40 + kb * 8];
        #pragma unroll
        for (int j = 0; j < 8; ++j) {
            bf16x8 b = *(const bf16x8*)&Bs[(j * 16 + lx) * 40 + kb * 8];
            acc[j] = __builtin_amdgcn_mfma_f32_16x16x32_bf16(a, b, acc[j], 0, 0, 0);
        }
    }
    #pragma unroll
    for (int j = 0; j < 8; ++j) {
        int c = half * 128 + j * 16 + lx;
        #pragma unroll
        for (int r_ = 0; r_ < 4; ++r_) {
            int n2 = nb + wave * 16 + kb * 4 + r_;
            if (n2 < NN) hw[(size_t)n2 * 256 + c] = acc[j][r_];
        }
    }
}

// per-node CSR aggregation: float4 lanes + 4-edge unroll; no atomics.
// agg[n] = [mean(128) | sum(128) | max(128)]
__global__ __launch_bounds__(256) void agg_kernel(const float* __restrict__ hw,
                                                  const float* __restrict__ btab,
                                                  const int* __restrict__ offsets,
                                                  const int* __restrict__ perm,
                                                  float* __restrict__ agg) {
    int t = threadIdx.x;
    int n = blockIdx.x * 8 + (t >> 5);
    int f = (t & 31) * 4;
    if (n >= NN) return;
    int s0 = offsets[n];
    int d = offsets[n + 1] - s0;
    f32x4 sum = {0.f, 0.f, 0.f, 0.f};
    f32x4 mx = {-INFINITY, -INFINITY, -INFINITY, -INFINITY};
    int i = 0;
    for (; i + 4 <= d; i += 4) {
        int p0 = perm[s0 + i], p1 = perm[s0 + i + 1];
        int p2 = perm[s0 + i + 2], p3 = perm[s0 + i + 3];
        f32x4 a0 = *(const f32x4*)(hw + (size_t)(p0 & 16383) * 256 + f);
        f32x4 a1 = *(const f32x4*)(hw + (size_t)(p1 & 16383) * 256 + f);
        f32x4 a2 = *(const f32x4*)(hw + (size_t)(p2 & 16383) * 256 + f);
        f32x4 a3 = *(const f32x4*)(hw + (size_t)(p3 & 16383) * 256 + f);
        f32x4 b0 = *(const f32x4*)(btab + (p0 >> 14) * HD + f);
        f32x4 b1 = *(const f32x4*)(btab + (p1 >> 14) * HD + f);
        f32x4 b2 = *(const f32x4*)(btab + (p2 >> 14) * HD + f);
        f32x4 b3 = *(const f32x4*)(btab + (p3 >> 14) * HD + f);
        f32x4 v0 = a0 + b0, v1 = a1 + b1, v2 = a2 + b2, v3 = a3 + b3;
        sum += v0 + v1 + v2 + v3;
        #pragma unroll
        for (int q = 0; q < 4; ++q)
            mx[q] = fmaxf(fmaxf(fmaxf(mx[q], v0[q]), fmaxf(v1[q], v2[q])), v3[q]);
    }
    for (; i < d; ++i) {
        int p0 = perm[s0 + i];
        f32x4 v0 = *(const f32x4*)(hw + (size_t)(p0 & 16383) * 256 + f)
                 + *(const f32x4*)(btab + (p0 >> 14) * HD + f);
        sum += v0;
        #pragma unroll
        for (int q = 0; q < 4; ++q) mx[q] = fmaxf(mx[q], v0[q]);
    }
    f32x4 c = *(const f32x4*)(hw + (size_t)n * 256 + 128 + f);
    f32x4 mean, so, mo;
    if (d > 0) {
        float df = (float)d, di = 1.f / df;
        so = sum + df * c;
        mean = sum * di + c;
        mo = mx + c;
    } else {
        so = (f32x4){0.f,0.f,0.f,0.f}; mean = so; mo = so;
    }
    *(f32x4*)(agg + (size_t)n * 384 + f) = mean;
    *(f32x4*)(agg + (size_t)n * 384 + 128 + f) = so;
    *(f32x4*)(agg + (size_t)n * 384 + 256 + f) = mo;
}

// (N,1280)@(1280,128), hcat on the fly. M_blk=32 (2 waves), grid.y = K-split (2).
// hcat regions (128 wide): r<9: agg[r%3] * {1,amp,att}[r/3]; r==9: h_in.
__global__ __launch_bounds__(128) void node_gemm_mfma(
    const float* __restrict__ agg, const float* __restrict__ hin,
    const float* __restrict__ amp, const float* __restrict__ att,
    const short* __restrict__ Wt /*[128][1280]*/,
    float* __restrict__ part) {
    __shared__ short As[32 * 40];
    __shared__ short Bs[128 * 40];
    int t = threadIdx.x;
    int nb = blockIdx.x * 32;
    int kbeg = blockIdx.y * 640;
    int wave = t >> 6, lane = t & 63;
    int arow = t >> 2, akl = (t & 3) * 8;
    int an = nb + arow;
    bool aval = an < NN;
    float f_amp = 0.f, f_att = 0.f;
    if (aval) { f_amp = amp[an]; f_att = att[an]; }
    int lx = lane & 15, kb = lane >> 4;
    int frow = wave * 16 + lx;
    f32x4 acc[8];
    #pragma unroll
    for (int j = 0; j < 8; ++j) acc[j] = (f32x4){0.f, 0.f, 0.f, 0.f};
    const short* Wrow = Wt + (size_t)t * 1280;

    for (int k0 = kbeg; k0 < kbeg + 640; k0 += 32) {
        __syncthreads();
        {   // stage A: 32 rows x 32 k of hcat, fp32 -> bf16
            int r = k0 >> 7;
            float v[8];
            if (aval) {
                if (r < 9) {
                    int ag = r % 3, fi = r / 3;
                    float fac = (fi == 0) ? 1.f : ((fi == 1) ? f_amp : f_att);
                    const float* src = agg + (size_t)an * 384 + ag * 128 + (k0 & 127) + akl;
                    float4 x0 = *(const float4*)src, x1 = *(const float4*)(src + 4);
                    v[0]=x0.x*fac; v[1]=x0.y*fac; v[2]=x0.z*fac; v[3]=x0.w*fac;
                    v[4]=x1.x*fac; v[5]=x1.y*fac; v[6]=x1.z*fac; v[7]=x1.w*fac;
                } else {
                    const float* src = hin + (size_t)an * HD + (k0 & 127) + akl;
                    float4 x0 = *(const float4*)src, x1 = *(const float4*)(src + 4);
                    v[0]=x0.x; v[1]=x0.y; v[2]=x0.z; v[3]=x0.w;
                    v[4]=x1.x; v[5]=x1.y; v[6]=x1.z; v[7]=x1.w;
                }
            } else {
                #pragma unroll
                for (int q = 0; q < 8; ++q) v[q] = 0.f;
            }
            bf16x8 pk;
            #pragma unroll
            for (int q = 0; q < 8; ++q) pk[q] = f2bf(v[q]);
            *(bf16x8*)&As[arow * 40 + akl] = pk;
        }
        {   // stage B
            const short* src = Wrow + k0;
            #pragma unroll
            for (int q = 0; q < 4; ++q)
                *(bf16x8*)&Bs[t * 40 + q * 8] = *(const bf16x8*)(src + q * 8);
        }
        __syncthreads();
        bf16x8 a = *(const bf16x8*)&As[frow * 40 + kb * 8];
        #pragma unroll
        for (int j = 0; j < 8; ++j) {
            bf16x8 b = *(const bf16x8*)&Bs[(j * 16 + lx) * 40 + kb * 8];
            acc[j] = __builtin_amdgcn_mfma_f32_16x16x32_bf16(a, b, acc[j], 0, 0, 0);
        }
    }
    float* po = part + (size_t)blockIdx.y * NN * HD;
    #pragma unroll
    for (int j = 0; j < 8; ++j) {
        int c = j * 16 + lx;
        #pragma unroll
        for (int r_ = 0; r_ < 4; ++r_) {
            int n2 = nb + wave * 16 + kb * 4 + r_;
            if (n2 < NN) po[(size_t)n2 * HD + c] = acc[j][r_];
        }
    }
}

__global__ void reduce_kernel(const float* __restrict__ part, const float* __restrict__ bias,
                              const float* __restrict__ hin, float* __restrict__ hout) {
    int idx = blockIdx.x * 256 + threadIdx.x;
    if (idx < NN * HD) {
        int f = idx & 127;
        hout[idx] = part[idx] + part[(size_t)NN * HD + idx] + bias[f] + hin[idx];
    }
}

// Fused deterministic graph pooling + output MLP. One block per graph (batch sorted).
__global__ __launch_bounds__(256) void pool_out_kernel(
    const float* __restrict__ h, const int* __restrict__ batch,
    const float* __restrict__ W1, const float* __restrict__ b1,
    const float* __restrict__ W2, const float* __restrict__ b2,
    float* __restrict__ out)
{
    __shared__ float rs[384];
    __shared__ float red[256];
    __shared__ float s2[128], m2[128];
    int g = blockIdx.x, t = threadIdx.x;
    // lower_bound(g) and lower_bound(g+1) on sorted batch
    int lo = 0, hi = NN;
    while (lo < hi) { int mid = (lo + hi) >> 1; if (batch[mid] < g) lo = mid + 1; else hi = mid; }
    int lo2 = lo, hi2 = NN;
    while (lo2 < hi2) { int mid = (lo2 + hi2) >> 1; if (batch[mid] < g + 1) lo2 = mid + 1; else hi2 = mid; }
    int cnt = lo2 - lo;
    int f = t & 127, grp = t >> 7;
    float sum = 0.f, mx = -INFINITY;
    for (int n = lo + grp; n < lo2; n += 2) {
        float v = h[(size_t)n * HD + f];
        sum += v; mx = fmaxf(mx, v);
    }
    if (grp == 1) { s2[f] = sum; m2[f] = mx; }
    __syncthreads();
    if (grp == 0) {
        sum += s2[f]; mx = fmaxf(mx, m2[f]);
        float mean = (cnt > 0) ? sum / (float)cnt : 0.f;
        float so = (cnt > 0) ? sum : 0.f;
        float mo = (cnt > 0) ? mx : 0.f;
        if (isnan(mean) || isinf(mean)) mean = 0.f;
        if (isnan(so) || isinf(so)) so = 0.f;
        if (isnan(mo) || isinf(mo)) mo = 0.f;
        rs[f] = mean; rs[128 + f] = so; rs[256 + f] = mo;
    }
    __syncthreads();
    {   // r @ W1: j = t&127, k-half = t>>7
        int j = t & 127, kh = t >> 7;
        float acc = 0.f;
        for (int k = kh * 192; k < kh * 192 + 192; ++k)
            acc = fmaf(rs[k], W1[k * HD + j], acc);
        red[t] = acc;
    }
    __syncthreads();
    if (t < 128) {
        float v = fmaxf(red[t] + red[128 + t] + b1[t], 0.f);
        red[t] = v * W2[t];
    }
    __syncthreads();
    for (int s = 64; s > 0; s >>= 1) {
        if (t < s) red[t] += red[t + s];
        __syncthreads();
    }
    if (t == 0) {
        float o = red[0] + b2[0];
        if (isnan(o) || isinf(o)) o = 0.f;
        out[g] = o;
    }
}

extern "C" void kernel_launch(void* const* d_in, const int* in_sizes, int n_in,
                              void* d_out, int out_size, void* d_ws, size_t ws_size,
                              hipStream_t stream)
{
    const int* x          = (const int*)d_in[0];
    const int* ei         = (const int*)d_in[1];
    const int* ea         = (const int*)d_in[2];
    const int* batch      = (const int*)d_in[3];
    const float* atom_emb = (const float*)d_in[4];
    const float* bond_emb = (const float*)d_in[5];
    const float* pre_W    = (const float*)d_in[6];
    const float* pre_b    = (const float*)d_in[7];
    const float* post_W   = (const float*)d_in[8];
    const float* post_b   = (const float*)d_in[9];
    const float* out_W1   = (const float*)d_in[10];
    const float* out_b1   = (const float*)d_in[11];
    const float* out_W2   = (const float*)d_in[12];
    const float* out_b2   = (const float*)d_in[13];
    float* out = (float*)d_out;
    const int* row = ei;
    const int* col = ei + NE;

    char* p = (char*)d_ws;
    auto alloc = [&](size_t bytes) { char* r = p; p += (bytes + 255) & ~(size_t)255; return r; };
    float*    deg     = (float*)alloc((size_t)NN * 4);
    float*    amp     = (float*)alloc((size_t)NN * 4);
    float*    att     = (float*)alloc((size_t)NN * 4);
    int*      offsets = (int*)alloc((size_t)(NN + 1) * 4);
    int*      cursor  = (int*)alloc((size_t)NN * 4);
    int*      perm    = (int*)alloc((size_t)NE * 4);
    float*    hA      = (float*)alloc((size_t)NN * HD * 4);
    float*    hB      = (float*)alloc((size_t)NN * HD * 4);
    float*    hw      = (float*)alloc((size_t)NN * 256 * 4);
    float*    agg     = (float*)alloc((size_t)NN * 384 * 4);
    float*    part    = (float*)alloc((size_t)2 * NN * HD * 4);
    float*    btab    = (float*)alloc((size_t)NL * 5 * HD * 4);
    short*    pre_Wt  = (short*)alloc((size_t)NL * 256 * 128 * 2);
    short*    post_Wt = (short*)alloc((size_t)NL * 128 * 1280 * 2);

    embed_kernel<<<(NN * HD) / 256, 256, 0, stream>>>(x, atom_emb, hA, deg, cursor);
    deg_kernel<<<(NE + 255) / 256, 256, 0, stream>>>(col, deg);
    facs_kernel<<<(NN + 255) / 256, 256, 0, stream>>>(deg, amp, att);
    scan_kernel<<<1, 1024, 0, stream>>>(deg, offsets);
    scatter_kernel<<<(NE + 255) / 256, 256, 0, stream>>>(row, col, ea, offsets, cursor, perm);
    bondtab_kernel<<<NL * 5, 128, 0, stream>>>(bond_emb, pre_W, pre_b, btab);
    convert_w_kernel<<<(NL * 128 * 1280 + 255) / 256, 256, 0, stream>>>(pre_W, post_W,
                                                                        pre_Wt, post_Wt);

    float* curH = hA;
    float* nxtH = hB;
    for (int l = 0; l < NL; ++l) {
        pre_gemm_mfma<<<dim3((NN + 31) / 32, 2), 128, 0, stream>>>(
            curH, pre_Wt + (size_t)l * 256 * 128, hw);
        agg_kernel<<<(NN + 7) / 8, 256, 0, stream>>>(hw, btab + (size_t)l * 5 * HD,
                                                     offsets, perm, agg);
        node_gemm_mfma<<<dim3((NN + 31) / 32, 2), 128, 0, stream>>>(
            agg, curH, amp, att, post_Wt + (size_t)l * 128 * 1280, part);
        reduce_kernel<<<(NN * HD) / 256, 256, 0, stream>>>(
            part, post_b + (size_t)l * HD, curH, nxtH);
        float* tmp = curH; curH = nxtH; nxtH = tmp;
    }

    pool_out_kernel<<<NG, 256, 0, stream>>>(curH, batch, out_W1, out_b1, out_W2, out_b2, out);
}

// Round 5
// 392.577 us; speedup vs baseline: 5.3730x; 1.0155x over previous
//
#include <hip/hip_runtime.h>
#include <hip/hip_bf16.h>
#include <math.h>

#define NN 10000
#define NE 160000
#define HD 128
#define NL 4
#define NG 64

typedef __attribute__((ext_vector_type(8))) short bf16x8;
typedef __attribute__((ext_vector_type(4))) short bf16x4;
typedef __attribute__((ext_vector_type(4))) float f32x4;

// fp32 -> bf16 (round to nearest even), finite inputs
static __device__ __forceinline__ short f2bf(float f) {
    unsigned u = __float_as_uint(f);
    unsigned r = (u + 0x7FFFu + ((u >> 16) & 1u)) >> 16;
    return (short)r;
}
static __device__ __forceinline__ float bf2f(short s) {
    return __uint_as_float(((unsigned)(unsigned short)s) << 16);
}

__global__ void embed_kernel(const int* __restrict__ x, const float* __restrict__ atom_emb,
                             float* __restrict__ h, float* __restrict__ deg,
                             int* __restrict__ cursor) {
    int idx = blockIdx.x * 256 + threadIdx.x;
    if (idx < NN) { deg[idx] = 0.f; cursor[idx] = 0; }
    if (idx < NN * HD) {
        int n = idx >> 7, f = idx & 127;
        h[idx] = atom_emb[x[n] * HD + f];
    }
}

__global__ void deg_kernel(const int* __restrict__ col, float* __restrict__ deg) {
    int e = blockIdx.x * 256 + threadIdx.x;
    if (e < NE) atomicAdd(&deg[col[e]], 1.f);
}

__global__ void facs_kernel(const float* __restrict__ deg, float* __restrict__ amp,
                            float* __restrict__ att) {
    int n = blockIdx.x * 256 + threadIdx.x;
    if (n < NN) {
        float logD = logf(deg[n] + 1.f);
        amp[n] = logD;                       // / AVG_D_LOG (=1.0)
        att[n] = 1.f / fmaxf(logD, 1e-8f);   // AVG_D_LOG / max(logD, eps)
    }
}

// exclusive prefix sum of (int)deg over NN entries, offsets[NN] = total (=NE)
__global__ __launch_bounds__(1024) void scan_kernel(const float* __restrict__ deg,
                                                    int* __restrict__ offsets) {
    __shared__ int s[1024];
    __shared__ int carry_s;
    int t = threadIdx.x;
    if (t == 0) carry_s = 0;
    __syncthreads();
    for (int c = 0; c < 10; ++c) {
        int i = c * 1024 + t;
        int v = (i < NN) ? (int)deg[i] : 0;
        s[t] = v;
        __syncthreads();
        for (int off = 1; off < 1024; off <<= 1) {
            int x2 = (t >= off) ? s[t - off] : 0;
            __syncthreads();
            s[t] += x2;
            __syncthreads();
        }
        int excl = carry_s + s[t] - v;
        if (i <= NN) offsets[i] = excl;
        __syncthreads();
        if (t == 1023) carry_s += s[1023];
        __syncthreads();
    }
}

__global__ void scatter_kernel(const int* __restrict__ row, const int* __restrict__ col,
                               const int* __restrict__ ea, const int* __restrict__ offsets,
                               int* __restrict__ cursor, int* __restrict__ perm) {
    int e = blockIdx.x * 256 + threadIdx.x;
    if (e < NE) {
        int c = col[e];
        int pos = offsets[c] + atomicAdd(&cursor[c], 1);
        perm[pos] = row[e] | (ea[e] << 14);   // row < 16384, ea < 5
    }
}

// btab[l][b][f] = bond_emb[b] @ pre_W[l][256:384] + pre_b[l]
__global__ void bondtab_kernel(const float* __restrict__ bond_emb,
                               const float* __restrict__ pre_W, const float* __restrict__ pre_b,
                               float* __restrict__ btab) {
    int lb = blockIdx.x;
    int l = lb / 5, b = lb % 5;
    int f = threadIdx.x;
    const float* W2 = pre_W + (size_t)l * 384 * HD + 256 * HD;
    const float* eb = bond_emb + b * HD;
    float acc = pre_b[l * HD + f];
    for (int k = 0; k < HD; ++k) acc = fmaf(eb[k], W2[k * HD + f], acc);
    btab[(l * 5 + b) * HD + f] = acc;
}

// Transposed bf16 weights:
//  pre_Wt[l][j][k] (j<256,k<128): j<128 -> pre_W[l][k][j]; else pre_W[l][128+k][j-128]
//  post_Wt[l][n][k] (n<128,k<1280): post_W[l][k][n]
__global__ void convert_w_kernel(const float* __restrict__ pre_W, const float* __restrict__ post_W,
                                 short* __restrict__ pre_Wt, short* __restrict__ post_Wt) {
    int idx = blockIdx.x * 256 + threadIdx.x;
    if (idx < NL * 256 * 128) {
        int l = idx / (256 * 128), r = idx % (256 * 128);
        int j = r >> 7, k = r & 127;
        const float* Wl = pre_W + (size_t)l * 384 * HD;
        float v = (j < HD) ? Wl[k * HD + j] : Wl[(HD + k) * HD + (j - HD)];
        pre_Wt[idx] = f2bf(v);
    }
    if (idx < NL * 128 * 1280) {
        int l = idx / (128 * 1280), r = idx % (128 * 1280);
        int n = r / 1280, k = r % 1280;
        post_Wt[idx] = f2bf(post_W[(size_t)l * 1280 * HD + (size_t)k * HD + n]);
    }
}

// hw0[n][0:128] = h[n] @ W0 (bf16, gather target), hw1[n][0:128] = h[n] @ W1 (fp32, self).
// M_blk=32 (2 waves), grid.y = half (0 -> hw0, 1 -> hw1).
__global__ __launch_bounds__(128) void pre_gemm_mfma(const float* __restrict__ h,
                                                     const short* __restrict__ Wt,  // [256][128]
                                                     short* __restrict__ hw0,
                                                     float* __restrict__ hw1) {
    __shared__ short As[32 * 40];
    __shared__ short Bs[128 * 40];
    int t = threadIdx.x;
    int nb = blockIdx.x * 32;
    int half = blockIdx.y;
    int wave = t >> 6, lane = t & 63;
    int arow = t >> 2, akl = (t & 3) * 8;
    int an = nb + arow;
    bool aval = an < NN;
    int lx = lane & 15, kb = lane >> 4;
    int frow = wave * 16 + lx;
    f32x4 acc[8];
    #pragma unroll
    for (int j = 0; j < 8; ++j) acc[j] = (f32x4){0.f, 0.f, 0.f, 0.f};
    const short* Wrow = Wt + (size_t)(half * 128 + t) * 128;

    for (int k0 = 0; k0 < 128; k0 += 32) {
        __syncthreads();
        {   // stage A: 32 rows x 32 k, fp32 -> bf16
            float v[8];
            if (aval) {
                const float* src = h + (size_t)an * HD + k0 + akl;
                float4 x0 = *(const float4*)src, x1 = *(const float4*)(src + 4);
                v[0]=x0.x; v[1]=x0.y; v[2]=x0.z; v[3]=x0.w;
                v[4]=x1.x; v[5]=x1.y; v[6]=x1.z; v[7]=x1.w;
            } else {
                #pragma unroll
                for (int q = 0; q < 8; ++q) v[q] = 0.f;
            }
            bf16x8 pk;
            #pragma unroll
            for (int q = 0; q < 8; ++q) pk[q] = f2bf(v[q]);
            *(bf16x8*)&As[arow * 40 + akl] = pk;
        }
        {   // stage B: 128 cols x 32 k from Wt (bf16, contiguous)
            const short* src = Wrow + k0;
            #pragma unroll
            for (int q = 0; q < 4; ++q)
                *(bf16x8*)&Bs[t * 40 + q * 8] = *(const bf16x8*)(src + q * 8);
        }
        __syncthreads();
        bf16x8 a = *(const bf16x8*)&As[frow * 40 + kb * 8];
        #pragma unroll
        for (int j = 0; j < 8; ++j) {
            bf16x8 b = *(const bf16x8*)&Bs[(j * 16 + lx) * 40 + kb * 8];
            acc[j] = __builtin_amdgcn_mfma_f32_16x16x32_bf16(a, b, acc[j], 0, 0, 0);
        }
    }
    #pragma unroll
    for (int j = 0; j < 8; ++j) {
        int c = j * 16 + lx;
        #pragma unroll
        for (int r_ = 0; r_ < 4; ++r_) {
            int n2 = nb + wave * 16 + kb * 4 + r_;
            if (n2 < NN) {
                if (half == 0) hw0[(size_t)n2 * HD + c] = f2bf(acc[j][r_]);
                else           hw1[(size_t)n2 * HD + c] = acc[j][r_];
            }
        }
    }
}

// per-node CSR aggregation: bf16 gathers (8B/lane) + 4-edge unroll; no atomics.
// agg[n] = [mean(128) | sum(128) | max(128)]
__global__ __launch_bounds__(256) void agg_kernel(const short* __restrict__ hw0,
                                                  const float* __restrict__ hw1,
                                                  const float* __restrict__ btab,
                                                  const int* __restrict__ offsets,
                                                  const int* __restrict__ perm,
                                                  float* __restrict__ agg) {
    int t = threadIdx.x;
    int n = blockIdx.x * 8 + (t >> 5);
    int f = (t & 31) * 4;
    if (n >= NN) return;
    int s0 = offsets[n];
    int d = offsets[n + 1] - s0;
    f32x4 sum = {0.f, 0.f, 0.f, 0.f};
    f32x4 mx = {-INFINITY, -INFINITY, -INFINITY, -INFINITY};
    int i = 0;
    for (; i + 4 <= d; i += 4) {
        int p0 = perm[s0 + i], p1 = perm[s0 + i + 1];
        int p2 = perm[s0 + i + 2], p3 = perm[s0 + i + 3];
        bf16x4 a0 = *(const bf16x4*)(hw0 + (size_t)(p0 & 16383) * HD + f);
        bf16x4 a1 = *(const bf16x4*)(hw0 + (size_t)(p1 & 16383) * HD + f);
        bf16x4 a2 = *(const bf16x4*)(hw0 + (size_t)(p2 & 16383) * HD + f);
        bf16x4 a3 = *(const bf16x4*)(hw0 + (size_t)(p3 & 16383) * HD + f);
        f32x4 b0 = *(const f32x4*)(btab + (p0 >> 14) * HD + f);
        f32x4 b1 = *(const f32x4*)(btab + (p1 >> 14) * HD + f);
        f32x4 b2 = *(const f32x4*)(btab + (p2 >> 14) * HD + f);
        f32x4 b3 = *(const f32x4*)(btab + (p3 >> 14) * HD + f);
        f32x4 v0, v1, v2, v3;
        #pragma unroll
        for (int q = 0; q < 4; ++q) {
            v0[q] = bf2f(a0[q]) + b0[q];
            v1[q] = bf2f(a1[q]) + b1[q];
            v2[q] = bf2f(a2[q]) + b2[q];
            v3[q] = bf2f(a3[q]) + b3[q];
        }
        sum += v0 + v1 + v2 + v3;
        #pragma unroll
        for (int q = 0; q < 4; ++q)
            mx[q] = fmaxf(fmaxf(fmaxf(mx[q], v0[q]), fmaxf(v1[q], v2[q])), v3[q]);
    }
    for (; i < d; ++i) {
        int p0 = perm[s0 + i];
        bf16x4 a0 = *(const bf16x4*)(hw0 + (size_t)(p0 & 16383) * HD + f);
        f32x4 b0 = *(const f32x4*)(btab + (p0 >> 14) * HD + f);
        f32x4 v0;
        #pragma unroll
        for (int q = 0; q < 4; ++q) v0[q] = bf2f(a0[q]) + b0[q];
        sum += v0;
        #pragma unroll
        for (int q = 0; q < 4; ++q) mx[q] = fmaxf(mx[q], v0[q]);
    }
    f32x4 c = *(const f32x4*)(hw1 + (size_t)n * HD + f);
    f32x4 mean, so, mo;
    if (d > 0) {
        float df = (float)d, di = 1.f / df;
        so = sum + df * c;
        mean = sum * di + c;
        mo = mx + c;
    } else {
        so = (f32x4){0.f,0.f,0.f,0.f}; mean = so; mo = so;
    }
    *(f32x4*)(agg + (size_t)n * 384 + f) = mean;
    *(f32x4*)(agg + (size_t)n * 384 + 128 + f) = so;
    *(f32x4*)(agg + (size_t)n * 384 + 256 + f) = mo;
}

// (N,1280)@(1280,128), hcat on the fly. M_blk=32 (2 waves), grid.y = K-split (2).
// hcat regions (128 wide): r<9: agg[r%3] * {1,amp,att}[r/3]; r==9: h_in.
__global__ __launch_bounds__(128) void node_gemm_mfma(
    const float* __restrict__ agg, const float* __restrict__ hin,
    const float* __restrict__ amp, const float* __restrict__ att,
    const short* __restrict__ Wt /*[128][1280]*/,
    float* __restrict__ part) {
    __shared__ short As[32 * 40];
    __shared__ short Bs[128 * 40];
    int t = threadIdx.x;
    int nb = blockIdx.x * 32;
    int kbeg = blockIdx.y * 640;
    int wave = t >> 6, lane = t & 63;
    int arow = t >> 2, akl = (t & 3) * 8;
    int an = nb + arow;
    bool aval = an < NN;
    float f_amp = 0.f, f_att = 0.f;
    if (aval) { f_amp = amp[an]; f_att = att[an]; }
    int lx = lane & 15, kb = lane >> 4;
    int frow = wave * 16 + lx;
    f32x4 acc[8];
    #pragma unroll
    for (int j = 0; j < 8; ++j) acc[j] = (f32x4){0.f, 0.f, 0.f, 0.f};
    const short* Wrow = Wt + (size_t)t * 1280;

    for (int k0 = kbeg; k0 < kbeg + 640; k0 += 32) {
        __syncthreads();
        {   // stage A: 32 rows x 32 k of hcat, fp32 -> bf16
            int r = k0 >> 7;
            float v[8];
            if (aval) {
                if (r < 9) {
                    int ag = r % 3, fi = r / 3;
                    float fac = (fi == 0) ? 1.f : ((fi == 1) ? f_amp : f_att);
                    const float* src = agg + (size_t)an * 384 + ag * 128 + (k0 & 127) + akl;
                    float4 x0 = *(const float4*)src, x1 = *(const float4*)(src + 4);
                    v[0]=x0.x*fac; v[1]=x0.y*fac; v[2]=x0.z*fac; v[3]=x0.w*fac;
                    v[4]=x1.x*fac; v[5]=x1.y*fac; v[6]=x1.z*fac; v[7]=x1.w*fac;
                } else {
                    const float* src = hin + (size_t)an * HD + (k0 & 127) + akl;
                    float4 x0 = *(const float4*)src, x1 = *(const float4*)(src + 4);
                    v[0]=x0.x; v[1]=x0.y; v[2]=x0.z; v[3]=x0.w;
                    v[4]=x1.x; v[5]=x1.y; v[6]=x1.z; v[7]=x1.w;
                }
            } else {
                #pragma unroll
                for (int q = 0; q < 8; ++q) v[q] = 0.f;
            }
            bf16x8 pk;
            #pragma unroll
            for (int q = 0; q < 8; ++q) pk[q] = f2bf(v[q]);
            *(bf16x8*)&As[arow * 40 + akl] = pk;
        }
        {   // stage B
            const short* src = Wrow + k0;
            #pragma unroll
            for (int q = 0; q < 4; ++q)
                *(bf16x8*)&Bs[t * 40 + q * 8] = *(const bf16x8*)(src + q * 8);
        }
        __syncthreads();
        bf16x8 a = *(const bf16x8*)&As[frow * 40 + kb * 8];
        #pragma unroll
        for (int j = 0; j < 8; ++j) {
            bf16x8 b = *(const bf16x8*)&Bs[(j * 16 + lx) * 40 + kb * 8];
            acc[j] = __builtin_amdgcn_mfma_f32_16x16x32_bf16(a, b, acc[j], 0, 0, 0);
        }
    }
    float* po = part + (size_t)blockIdx.y * NN * HD;
    #pragma unroll
    for (int j = 0; j < 8; ++j) {
        int c = j * 16 + lx;
        #pragma unroll
        for (int r_ = 0; r_ < 4; ++r_) {
            int n2 = nb + wave * 16 + kb * 4 + r_;
            if (n2 < NN) po[(size_t)n2 * HD + c] = acc[j][r_];
        }
    }
}

__global__ void reduce_kernel(const float* __restrict__ part, const float* __restrict__ bias,
                              const float* __restrict__ hin, float* __restrict__ hout) {
    int idx = blockIdx.x * 256 + threadIdx.x;
    if (idx < NN * HD) {
        int f = idx & 127;
        hout[idx] = part[idx] + part[(size_t)NN * HD + idx] + bias[f] + hin[idx];
    }
}

// Fused deterministic graph pooling + output MLP. One block per graph (batch sorted).
__global__ __launch_bounds__(256) void pool_out_kernel(
    const float* __restrict__ h, const int* __restrict__ batch,
    const float* __restrict__ W1, const float* __restrict__ b1,
    const float* __restrict__ W2, const float* __restrict__ b2,
    float* __restrict__ out)
{
    __shared__ float rs[384];
    __shared__ float red[256];
    __shared__ float s2[128], m2[128];
    int g = blockIdx.x, t = threadIdx.x;
    // lower_bound(g) and lower_bound(g+1) on sorted batch
    int lo = 0, hi = NN;
    while (lo < hi) { int mid = (lo + hi) >> 1; if (batch[mid] < g) lo = mid + 1; else hi = mid; }
    int lo2 = lo, hi2 = NN;
    while (lo2 < hi2) { int mid = (lo2 + hi2) >> 1; if (batch[mid] < g + 1) lo2 = mid + 1; else hi2 = mid; }
    int cnt = lo2 - lo;
    int f = t & 127, grp = t >> 7;
    float sum = 0.f, mx = -INFINITY;
    for (int n = lo + grp; n < lo2; n += 2) {
        float v = h[(size_t)n * HD + f];
        sum += v; mx = fmaxf(mx, v);
    }
    if (grp == 1) { s2[f] = sum; m2[f] = mx; }
    __syncthreads();
    if (grp == 0) {
        sum += s2[f]; mx = fmaxf(mx, m2[f]);
        float mean = (cnt > 0) ? sum / (float)cnt : 0.f;
        float so = (cnt > 0) ? sum : 0.f;
        float mo = (cnt > 0) ? mx : 0.f;
        if (isnan(mean) || isinf(mean)) mean = 0.f;
        if (isnan(so) || isinf(so)) so = 0.f;
        if (isnan(mo) || isinf(mo)) mo = 0.f;
        rs[f] = mean; rs[128 + f] = so; rs[256 + f] = mo;
    }
    __syncthreads();
    {   // r @ W1: j = t&127, k-half = t>>7
        int j = t & 127, kh = t >> 7;
        float acc = 0.f;
        for (int k = kh * 192; k < kh * 192 + 192; ++k)
            acc = fmaf(rs[k], W1[k * HD + j], acc);
        red[t] = acc;
    }
    __syncthreads();
    if (t < 128) {
        float v = fmaxf(red[t] + red[128 + t] + b1[t], 0.f);
        red[t] = v * W2[t];
    }
    __syncthreads();
    for (int s = 64; s > 0; s >>= 1) {
        if (t < s) red[t] += red[t + s];
        __syncthreads();
    }
    if (t == 0) {
        float o = red[0] + b2[0];
        if (isnan(o) || isinf(o)) o = 0.f;
        out[g] = o;
    }
}

extern "C" void kernel_launch(void* const* d_in, const int* in_sizes, int n_in,
                              void* d_out, int out_size, void* d_ws, size_t ws_size,
                              hipStream_t stream)
{
    const int* x          = (const int*)d_in[0];
    const int* ei         = (const int*)d_in[1];
    const int* ea         = (const int*)d_in[2];
    const int* batch      = (const int*)d_in[3];
    const float* atom_emb = (const float*)d_in[4];
    const float* bond_emb = (const float*)d_in[5];
    const float* pre_W    = (const float*)d_in[6];
    const float* pre_b    = (const float*)d_in[7];
    const float* post_W   = (const float*)d_in[8];
    const float* post_b   = (const float*)d_in[9];
    const float* out_W1   = (const float*)d_in[10];
    const float* out_b1   = (const float*)d_in[11];
    const float* out_W2   = (const float*)d_in[12];
    const float* out_b2   = (const float*)d_in[13];
    float* out = (float*)d_out;
    const int* row = ei;
    const int* col = ei + NE;

    char* p = (char*)d_ws;
    auto alloc = [&](size_t bytes) { char* r = p; p += (bytes + 255) & ~(size_t)255; return r; };
    float*    deg     = (float*)alloc((size_t)NN * 4);
    float*    amp     = (float*)alloc((size_t)NN * 4);
    float*    att     = (float*)alloc((size_t)NN * 4);
    int*      offsets = (int*)alloc((size_t)(NN + 1) * 4);
    int*      cursor  = (int*)alloc((size_t)NN * 4);
    int*      perm    = (int*)alloc((size_t)NE * 4);
    float*    hA      = (float*)alloc((size_t)NN * HD * 4);
    float*    hB      = (float*)alloc((size_t)NN * HD * 4);
    short*    hw0     = (short*)alloc((size_t)NN * HD * 2);
    float*    hw1     = (float*)alloc((size_t)NN * HD * 4);
    float*    agg     = (float*)alloc((size_t)NN * 384 * 4);
    float*    part    = (float*)alloc((size_t)2 * NN * HD * 4);
    float*    btab    = (float*)alloc((size_t)NL * 5 * HD * 4);
    short*    pre_Wt  = (short*)alloc((size_t)NL * 256 * 128 * 2);
    short*    post_Wt = (short*)alloc((size_t)NL * 128 * 1280 * 2);

    embed_kernel<<<(NN * HD) / 256, 256, 0, stream>>>(x, atom_emb, hA, deg, cursor);
    deg_kernel<<<(NE + 255) / 256, 256, 0, stream>>>(col, deg);
    facs_kernel<<<(NN + 255) / 256, 256, 0, stream>>>(deg, amp, att);
    scan_kernel<<<1, 1024, 0, stream>>>(deg, offsets);
    scatter_kernel<<<(NE + 255) / 256, 256, 0, stream>>>(row, col, ea, offsets, cursor, perm);
    bondtab_kernel<<<NL * 5, 128, 0, stream>>>(bond_emb, pre_W, pre_b, btab);
    convert_w_kernel<<<(NL * 128 * 1280 + 255) / 256, 256, 0, stream>>>(pre_W, post_W,
                                                                        pre_Wt, post_Wt);

    float* curH = hA;
    float* nxtH = hB;
    for (int l = 0; l < NL; ++l) {
        pre_gemm_mfma<<<dim3((NN + 31) / 32, 2), 128, 0, stream>>>(
            curH, pre_Wt + (size_t)l * 256 * 128, hw0, hw1);
        agg_kernel<<<(NN + 7) / 8, 256, 0, stream>>>(hw0, hw1, btab + (size_t)l * 5 * HD,
                                                     offsets, perm, agg);
        node_gemm_mfma<<<dim3((NN + 31) / 32, 2), 128, 0, stream>>>(
            agg, curH, amp, att, post_Wt + (size_t)l * 128 * 1280, part);
        reduce_kernel<<<(NN * HD) / 256, 256, 0, stream>>>(
            part, post_b + (size_t)l * HD, curH, nxtH);
        float* tmp = curH; curH = nxtH; nxtH = tmp;
    }

    pool_out_kernel<<<NG, 256, 0, stream>>>(curH, batch, out_W1, out_b1, out_W2, out_b2, out);
}